// Round 7
// baseline (84.813 us; speedup 1.0000x reference)
//
#include <hip/hip_runtime.h>

#define NWIDTH 299592
#define NOUT   51360

typedef unsigned long long ull;

// ---------- Lyndon machinery (rebuilt every launch; deterministic) ----------

__device__ __forceinline__ bool is_lyndon(unsigned p, int n) {
  const unsigned nb = 3u * (unsigned)n;
  const unsigned mask = (1u << nb) - 1u;
  for (int k = 1; k < n; ++k) {
    unsigned rot = ((p << (3 * k)) & mask) | (p >> (nb - 3 * k));
    if (p >= rot) return false;   // strictly smaller than every proper rotation
  }
  return true;
}

__device__ __forceinline__ int lbound(const int* __restrict__ a, int lo, int hi, int v) {
  while (lo < hi) { int m = (lo + hi) >> 1; if (a[m] < v) lo = m + 1; else hi = m; }
  return lo;
}

// ONE fused prep kernel (257 blocks):
//  blocks 0..255 : level-6 masks (mask64) + per-block counts (blkcnt)
//  block 256     : levels 1..5 -> idx_table (7764 entries)
//  last-arriving block (atomic done-counter): grp_off (4096), cnt8 (8), range_tab (64)
__global__ __launch_bounds__(1024) void lyndon_all(int* __restrict__ idx_table,
                                                   int* __restrict__ blkcnt,
                                                   ull* __restrict__ mask64,
                                                   int* __restrict__ grp_off,
                                                   int* __restrict__ range_tab,
                                                   int* __restrict__ cnt8,
                                                   int* __restrict__ done) {
  const int tid = threadIdx.x, lane = tid & 63, wv = tid >> 6;
  __shared__ int wsum[16];
  __shared__ int bc[256];
  __shared__ int s_flag;

  if (blockIdx.x < 256) {
    const unsigned p = blockIdx.x * 1024u + (unsigned)tid;
    bool f = is_lyndon(p, 6);
    ull m = __ballot(f);
    if (lane == 0) { mask64[blockIdx.x * 16 + wv] = m; wsum[wv] = __popcll(m); }
    __syncthreads();
    if (tid == 0) {
      int s = 0;
      for (int i = 0; i < 16; ++i) s += wsum[i];
      blkcnt[blockIdx.x] = s;
    }
  } else {
    // levels 1..5: shuffle-scan per level
    const int sizes[5] = {8, 64, 512, 4096, 32768};
    const int offs[5]  = {0, 8, 72, 584, 4680};     // sig flat offsets
    const int bases[5] = {0, 8, 36, 204, 1212};     // out slot bases
#pragma unroll
    for (int li = 0; li < 5; ++li) {
      const int n = li + 1, sz = sizes[li];
      const int per = (sz + 1023) >> 10;
      const int start = tid * per;
      int c = 0;
      for (int j = 0; j < per; ++j) {
        int p = start + j;
        if (p < sz && is_lyndon((unsigned)p, n)) ++c;
      }
      int pref = c;
      for (int d = 1; d < 64; d <<= 1) { int t = __shfl_up(pref, d); if (lane >= d) pref += t; }
      if (lane == 63) wsum[wv] = pref;
      __syncthreads();
      int wbase = 0;
      for (int i = 0; i < wv; ++i) wbase += wsum[i];
      int excl = wbase + pref - c;
      int w = 0;
      for (int j = 0; j < per; ++j) {
        int p = start + j;
        if (p < sz && is_lyndon((unsigned)p, n)) {
          idx_table[bases[li] + excl + w] = offs[li] + p;
          ++w;
        }
      }
      __syncthreads();
    }
  }

  // ---- last-block election ----
  __syncthreads();
  if (tid == 0) {
    __threadfence();                      // release this block's global writes
    s_flag = (atomicAdd(done, 1) == 256); // 257th arrival finishes up
  }
  __syncthreads();
  if (!s_flag) return;
  __threadfence();                        // acquire all blocks' writes

  // scan blkcnt (inclusive) in LDS
  if (tid < 256) bc[tid] = blkcnt[tid];
  __syncthreads();
  for (int d = 1; d < 256; d <<= 1) {
    int t = (tid >= d && tid < 256) ? bc[tid - d] : 0;
    __syncthreads();
    if (tid < 256) bc[tid] += t;
    __syncthreads();
  }
  // grp_off: thread t -> groups 4t..4t+3 (4096 groups total)
  {
    const int g0 = tid * 4;
    const int B = g0 >> 4;       // mask-block id (16 groups each)
    const int q = tid & 3;       // quarter within mask-block
    ull m0 = mask64[g0], m1 = mask64[g0 + 1], m2 = mask64[g0 + 2], m3 = mask64[g0 + 3];
    int p0 = __popcll(m0), p1 = __popcll(m1), p2 = __popcll(m2), p3 = __popcll(m3);
    int s = p0 + p1 + p2 + p3;
    int u1 = __shfl_up(s, 1), u2 = __shfl_up(s, 2), u3 = __shfl_up(s, 3);
    int pre = (q >= 1 ? u1 : 0) + (q >= 2 ? u2 : 0) + (q >= 3 ? u3 : 0);
    int run = (B ? bc[B - 1] : 0) + pre;
    grp_off[g0] = run; run += p0;
    grp_off[g0 + 1] = run; run += p1;
    grp_off[g0 + 2] = run; run += p2;
    grp_off[g0 + 3] = run;
  }
  // per-j1 level-6 counts (32 mask-blocks per j1)
  if (tid < 8) {
    int hi = bc[tid * 32 + 31];
    int lo = tid ? bc[tid * 32 - 1] : 0;
    cnt8[tid] = hi - lo;
  }
  // range table: levels 2..5, per j1, [a0,a1) in idx-slot space
  if (tid < 64) {
    const int goff[4]  = {8, 72, 584, 4680};
    const int gbase[4] = {8, 36, 204, 1212};
    const int gcnt[4]  = {28, 168, 1008, 6552};
    const int gsub[4]  = {8, 64, 512, 4096};
    const int ki = tid >> 4, j = (tid >> 1) & 7, which = tid & 1;
    const int v = goff[ki] + (j + which) * gsub[ki];
    range_tab[tid] = lbound(idx_table, gbase[ki], gbase[ki] + gcnt[ki], v);
  }
}

// ---------- main: per-(batch, first-letter) log-signature slice ----------
//
// L = S + sum_n coef_n S^{(x)n}. With A_i = sum_m coef_{m+1} P_i^{(m)},
// L6 = S6 + A5(x)S1 + A4(x)S2 + A3(x)S3 + A2(x)S4 + coef2*p1*S5.
// Horner iterates only P2..P5 (ping-pong LDS, 1 barrier/iter); L6 evaluated
// either by coalesced stream + ballot-rank scatter (dense j1) or per-group
// bit-iteration with point loads (sparse j1: counts {561,110,9,0} for j1>=4).
// mask/rank tables preloaded to LDS (no dependent global loads in the loop).
//
// LDS layout (16304 floats = 65.2 KiB; 2 blocks/CU):
//  PA@0[584] PB@584[584] (Horner ping-pong; PA reused for L2/L3/L4 after)
//  L5@1168[4096] | A2@5264[8] A3@5272[64] A4@5336[512] A5@5848[4096]
//  S2C@9944[64] S3C@10008[528p] S4C@10536[4224p] S1C@14760[8]
//  MK@14768[512 ull] GO@15792[512 int]

#define SM_PA  0
#define SM_PB  584
#define SM_L5  1168
#define SM_A2  5264
#define SM_A3  5272
#define SM_A4  5336
#define SM_A5  5848
#define SM_S2  9944
#define SM_S3  10008
#define SM_S4  10536
#define SM_S1  14760
#define SM_MK  14768
#define SM_GO  15792
#define SM_TOT 16304

__device__ __forceinline__ int pad32(int i) { return i + (i >> 5); }

__global__ __launch_bounds__(1024)
void logsig_main(const float* __restrict__ sig,
                 const int* __restrict__ idx_table,
                 const ull* __restrict__ mask64,
                 const int* __restrict__ grp_off,
                 const int* __restrict__ range_tab,
                 const int* __restrict__ cnt8,
                 float* __restrict__ out) {
  __shared__ __align__(16) float sm[SM_TOT];
  const int tid = threadIdx.x;
  const int bid = blockIdx.x;
  // XCD swizzle: all 8 j1-blocks of a batch land on one XCD (512 = 8 XCD x 64)
  const int xcd = bid & 7;
  const int g   = bid >> 3;
  const int b   = xcd * 8 + (g >> 3);
  const int j1  = g & 7;

  const float* __restrict__ S  = sig + (size_t)b * NWIDTH;
  const float* __restrict__ S2 = S + 8;
  const float* __restrict__ S3 = S + 72;
  const float* __restrict__ S4 = S + 584;
  const float* __restrict__ S5 = S + 4680;
  const float* __restrict__ S6 = S + 37448;

  const float p1 = S[j1];
  ull* mkL = (ull*)(sm + SM_MK);
  int* goL = (int*)(sm + SM_GO);

  // ---- pass 1: global -> LDS/regs ----
  if (tid < 8)   sm[SM_S1 + tid] = S[tid];
  if (tid < 64)  sm[SM_S2 + tid] = S2[tid];
  if (tid < 512) sm[SM_S3 + pad32(tid)] = S3[tid];
  {
    float4 v = *(const float4*)(S4 + tid * 4);
    int i0 = tid * 4;
    sm[SM_S4 + pad32(i0)]     = v.x;
    sm[SM_S4 + pad32(i0 + 1)] = v.y;
    sm[SM_S4 + pad32(i0 + 2)] = v.z;
    sm[SM_S4 + pad32(i0 + 3)] = v.w;
  }
  float p5[4], l5i[4];
  {
    float4 v = *(const float4*)(S5 + j1 * 4096 + tid * 4);
    p5[0] = v.x; p5[1] = v.y; p5[2] = v.z; p5[3] = v.w;
    l5i[0] = v.x; l5i[1] = v.y; l5i[2] = v.z; l5i[3] = v.w;
  }
  if (tid < 512) {
    mkL[tid] = mask64[j1 * 512 + tid];
    goL[tid] = grp_off[j1 * 512 + tid];
  }
  __syncthreads();

  // ---- pass 2: P^{(1)} slices from LDS caches; S1 register copies ----
  float s1q[4];
#pragma unroll
  for (int e = 0; e < 4; ++e) s1q[e] = sm[SM_S1 + ((tid & 1) << 2) + e];
  const float s1t = sm[SM_S1 + (tid & 7)];
  if (tid < 8)   sm[SM_PA + tid]      = sm[SM_S2 + j1 * 8 + tid];
  if (tid < 64)  sm[SM_PA + 8 + tid]  = sm[SM_S3 + pad32(j1 * 64 + tid)];
  if (tid < 512) sm[SM_PA + 72 + tid] = sm[SM_S4 + pad32(j1 * 512 + tid)];
  __syncthreads();

  float a5[4] = {0.f, 0.f, 0.f, 0.f};
  float a4 = 0.f, a3 = 0.f, a2 = 0.f;

  // ---- Horner on P2..P5, ping-pong buffers, 1 barrier/iter ----
  const float coefs[7] = {0.f, 0.f, -0.5f, 1.f / 3.f, -0.25f, 0.2f, -1.f / 6.f};
#pragma unroll
  for (int n = 2; n <= 5; ++n) {
    const float coef = coefs[n];
    const int RP = (n & 1) ? SM_PB : SM_PA;   // n=2 reads PA
    const int WP = (n & 1) ? SM_PA : SM_PB;
#pragma unroll
    for (int e = 0; e < 4; ++e) a5[e] += coef * p5[e];
    if (tid < 512) a4 += coef * sm[RP + 72 + tid];
    if (tid < 64)  a3 += coef * sm[RP + 8 + tid];
    if (tid < 8)   a2 += coef * sm[RP + tid];
    const float ph4 = sm[RP + 72 + (tid >> 1)];
    const float ph3 = sm[RP + 8 + (tid >> 4)];
    const float ph2 = sm[RP + (tid >> 7)];
    float np5[4];
#pragma unroll
    for (int e = 0; e < 4; ++e) {
      const int q = (tid << 2) + e;
      float acc = ph4 * s1q[e] + ph3 * sm[SM_S2 + (q & 63)]
                + ph2 * sm[SM_S3 + pad32(q & 511)];
      if (n == 2) acc += p1 * sm[SM_S4 + pad32(q)];
      np5[e] = acc;
    }
    float t4 = 0.f, t3 = 0.f, t2 = 0.f;
    if (tid < 512) {
      t4 = sm[RP + 8 + (tid >> 3)] * s1t
         + sm[RP + (tid >> 6)] * sm[SM_S2 + (tid & 63)];
      if (n == 2) t4 += p1 * sm[SM_S3 + pad32(tid)];
    }
    if (tid < 64) {
      t3 = sm[RP + (tid >> 3)] * s1t;
      if (n == 2) t3 += p1 * sm[SM_S2 + tid];
    }
    if (tid < 8) {
      if (n == 2) t2 = p1 * s1t;
    }
    if (tid < 512) sm[WP + 72 + tid] = t4;
    if (tid < 64)  sm[WP + 8 + tid]  = t3;
    if (tid < 8)   sm[WP + tid]      = t2;
#pragma unroll
    for (int e = 0; e < 4; ++e) p5[e] = np5[e];
    __syncthreads();
  }
#pragma unroll
  for (int e = 0; e < 4; ++e) a5[e] += coefs[6] * p5[e];   // n=6 term (level 5 only)

  // ---- dump A arrays ----
  if (tid < 8)   sm[SM_A2 + tid] = a2;
  if (tid < 64)  sm[SM_A3 + tid] = a3;
  if (tid < 512) sm[SM_A4 + tid] = a4;
  *(float4*)(sm + SM_A5 + tid * 4) = make_float4(a5[0], a5[1], a5[2], a5[3]);
  __syncthreads();

  // ---- closed-form L2..L5 into LDS (PA region + L5) ----
  const float c2p1 = -0.5f * p1;
  if (tid < 8)
    sm[SM_PA + tid] = sm[SM_S2 + j1 * 8 + tid] + c2p1 * s1t;
  if (tid < 64)
    sm[SM_PA + 8 + tid] = sm[SM_S3 + pad32(j1 * 64 + tid)]
                        + sm[SM_A2 + (tid >> 3)] * s1t
                        + c2p1 * sm[SM_S2 + tid];
  if (tid < 512)
    sm[SM_PA + 72 + tid] = sm[SM_S4 + pad32(j1 * 512 + tid)]
                         + sm[SM_A3 + (tid >> 3)] * s1t
                         + sm[SM_A2 + (tid >> 6)] * sm[SM_S2 + (tid & 63)]
                         + c2p1 * sm[SM_S3 + pad32(tid)];
  {
    float l5v[4];
#pragma unroll
    for (int e = 0; e < 4; ++e) {
      const int q = (tid << 2) + e;
      l5v[e] = l5i[e]
             + sm[SM_A4 + (tid >> 1)] * s1q[e]
             + sm[SM_A3 + (tid >> 4)] * sm[SM_S2 + (q & 63)]
             + sm[SM_A2 + (tid >> 7)] * sm[SM_S3 + pad32(q & 511)]
             + c2p1 * sm[SM_S4 + pad32(q)];
    }
    *(float4*)(sm + SM_L5 + tid * 4) = make_float4(l5v[0], l5v[1], l5v[2], l5v[3]);
  }
  float* outb = out + (size_t)b * NOUT;
  if (tid == 0) outb[j1] = p1;
  __syncthreads();

  // ---- gather levels 2..5 via precomputed ranges ----
  const int goff[6]   = {0, 0, 8, 72, 584, 4680};
  const int gsub[6]   = {0, 1, 8, 64, 512, 4096};
  const int ldsoff[6] = {0, 0, SM_PA, SM_PA + 8, SM_PA + 72, SM_L5};
#pragma unroll
  for (int k = 2; k <= 5; ++k) {
    const int rb = (k - 2) * 16 + j1 * 2;
    const int a0 = range_tab[rb];
    const int a1 = range_tab[rb + 1];
    const int v0 = goff[k] + j1 * gsub[k];
    for (int o = a0 + tid; o < a1; o += 1024) {
      int pl = idx_table[o] - v0;
      outb[o] = sm[ldsoff[k] + pl];
    }
  }

  // ---- level 6 ----
  const float* __restrict__ S6j = S6 + (size_t)j1 * 32768;
  const int cnt = cnt8[j1];
  if (cnt > 1536) {
    // dense: float4 coalesced stream + ballot-rank scatter (tables in LDS)
    const int t4i = tid << 2;
#pragma unroll 4
    for (int it = 0; it < 8; ++it) {
      const int pl0 = it * 4096 + t4i;
      const int gl  = pl0 >> 6;             // local group 0..511
      const ull m   = mkL[gl];
      const int gofs = goL[gl];
      const float4 x6 = *(const float4*)(S6j + pl0);
      const float4 x5 = *(const float4*)(S5 + pl0);
      const float x6a[4] = {x6.x, x6.y, x6.z, x6.w};
      const float x5a[4] = {x5.x, x5.y, x5.z, x5.w};
      const float a5v = sm[SM_A5 + (pl0 >> 3)];
      const float a4v = sm[SM_A4 + (pl0 >> 6)];
      const float a3v = sm[SM_A3 + (pl0 >> 9)];
      const float a2v = sm[SM_A2 + it];
      const int c63 = pl0 & 63, c511 = pl0 & 511, c4095 = pl0 & 4095;
#pragma unroll
      for (int e = 0; e < 4; ++e) {
        float v = x6a[e]
                + a5v * s1q[e]
                + a4v * sm[SM_S2 + c63 + e]
                + a3v * sm[SM_S3 + pad32(c511 + e)]
                + a2v * sm[SM_S4 + pad32(c4095 + e)]
                + c2p1 * x5a[e];
        if ((m >> (c63 + e)) & 1ull)
          outb[7764 + gofs + __popcll(m & ((1ull << (c63 + e)) - 1ull))] = v;
      }
    }
  } else if (cnt > 0) {
    // sparse: one group per thread, iterate set bits with point loads
    if (tid < 512) {
      ull m = mkL[tid];
      int slot = 7764 + goL[tid];
      const int g6 = tid << 6;
      while (m) {
        const int bit = __builtin_ctzll(m);
        const int pl = g6 + bit;
        float v = S6j[pl]
                + sm[SM_A5 + (pl >> 3)] * sm[SM_S1 + (pl & 7)]
                + sm[SM_A4 + tid] * sm[SM_S2 + (pl & 63)]
                + sm[SM_A3 + (pl >> 9)] * sm[SM_S3 + pad32(pl & 511)]
                + sm[SM_A2 + (pl >> 12)] * sm[SM_S4 + pad32(pl & 4095)]
                + c2p1 * S5[pl];
        outb[slot++] = v;
        m &= m - 1;
      }
    }
  }
}

// ---------- launch ----------
// d_ws layout: mask64[4096] ull | idx_table[7764] int | blkcnt[256] |
// grp_off[4096] | range_tab[64] | cnt8[8] | done[1]   (~82 KB)

extern "C" void kernel_launch(void* const* d_in, const int* in_sizes, int n_in,
                              void* d_out, int out_size, void* d_ws, size_t ws_size,
                              hipStream_t stream) {
  const float* sig = (const float*)d_in[0];
  float* out = (float*)d_out;
  ull* mask64    = (ull*)d_ws;                       // 4096 ull
  int* idx_table = (int*)(mask64 + 4096);            // 7764 int
  int* blkcnt    = idx_table + 7764;                 // 256
  int* grp_off   = blkcnt + 256;                     // 4096
  int* range_tab = grp_off + 4096;                   // 64
  int* cnt8      = range_tab + 64;                   // 8
  int* done      = cnt8 + 8;                         // 1

  hipMemsetAsync(done, 0, sizeof(int), stream);
  lyndon_all<<<257, 1024, 0, stream>>>(idx_table, blkcnt, mask64, grp_off,
                                       range_tab, cnt8, done);
  logsig_main<<<512, 1024, 0, stream>>>(sig, idx_table, mask64, grp_off,
                                        range_tab, cnt8, out);
}

// Round 8
// 70.448 us; speedup vs baseline: 1.2039x; 1.2039x over previous
//
#include <hip/hip_runtime.h>

#define NWIDTH 299592
#define NOUT   51360

typedef unsigned long long ull;

// Hardcoded Lyndon gather ranges (counts are fixed combinatorics):
// level-k output-slot base per first letter j1 (9 entries: j1=0..7 + end).
__device__ const int g_B2[9] = {8, 15, 21, 26, 30, 33, 35, 36, 36};
__device__ const int g_B3[9] = {36, 92, 134, 164, 184, 196, 202, 204, 204};
__device__ const int g_B4[9] = {204, 624, 897, 1062, 1152, 1194, 1209, 1212, 1212};
__device__ const int g_B5[9] = {1212, 4404, 6210, 7140, 7560, 7716, 7758, 7764, 7764};

// ---------- Lyndon machinery (rebuilt every launch; deterministic) ----------

__device__ __forceinline__ bool is_lyndon(unsigned p, int n) {
  const unsigned nb = 3u * (unsigned)n;
  const unsigned mask = (1u << nb) - 1u;
  for (int k = 1; k < n; ++k) {
    unsigned rot = ((p << (3 * k)) & mask) | (p >> (nb - 3 * k));
    if (p >= rot) return false;   // strictly smaller than every proper rotation
  }
  return true;
}

// blocks 0..255: level-6 counts. block 256: levels 1..5 -> idx_table.
__global__ __launch_bounds__(1024) void lyndon_stage1(int* __restrict__ idx_table,
                                                      int* __restrict__ blkcnt) {
  const int tid = threadIdx.x, lane = tid & 63, wv = tid >> 6;
  if (blockIdx.x < 256) {
    const unsigned p = blockIdx.x * 1024u + (unsigned)tid;
    bool f = is_lyndon(p, 6);
    unsigned long long m = __ballot(f);
    __shared__ int wsum[16];
    if (lane == 0) wsum[wv] = __popcll(m);
    __syncthreads();
    if (tid == 0) {
      int s = 0;
      for (int i = 0; i < 16; ++i) s += wsum[i];
      blkcnt[blockIdx.x] = s;
    }
    return;
  }
  __shared__ int ws[16];
  const int sizes[5] = {8, 64, 512, 4096, 32768};
  const int offs[5]  = {0, 8, 72, 584, 4680};     // sig flat offsets
  const int bases[5] = {0, 8, 36, 204, 1212};     // out slot bases
#pragma unroll
  for (int li = 0; li < 5; ++li) {
    const int n = li + 1, sz = sizes[li];
    const int per = (sz + 1023) >> 10;
    const int start = tid * per;
    int c = 0;
    for (int j = 0; j < per; ++j) {
      int p = start + j;
      if (p < sz && is_lyndon((unsigned)p, n)) ++c;
    }
    int pref = c;                                  // wave inclusive scan
    for (int d = 1; d < 64; d <<= 1) { int t = __shfl_up(pref, d); if (lane >= d) pref += t; }
    if (lane == 63) ws[wv] = pref;
    __syncthreads();
    int wbase = 0;
    for (int i = 0; i < wv; ++i) wbase += ws[i];
    int excl = wbase + pref - c;
    int w = 0;
    for (int j = 0; j < per; ++j) {
      int p = start + j;
      if (p < sz && is_lyndon((unsigned)p, n)) {
        idx_table[bases[li] + excl + w] = offs[li] + p;
        ++w;
      }
    }
    __syncthreads();
  }
}

// Per-64-group Lyndon mask + exclusive global rank offset.
__global__ __launch_bounds__(1024) void lyndon6_finish(const int* __restrict__ blkcnt,
                                                       ull* __restrict__ mask64,
                                                       int* __restrict__ grp_off) {
  const int tid = threadIdx.x, lane = tid & 63, wv = tid >> 6;
  __shared__ int wred[16];
  __shared__ int wsum[16];
  __shared__ int s_blockoff;
  int partial = (tid < (int)blockIdx.x) ? blkcnt[tid] : 0;
  for (int d = 32; d; d >>= 1) partial += __shfl_down(partial, d);
  if (lane == 0) wred[wv] = partial;
  __syncthreads();
  if (tid == 0) {
    int s = 0;
    for (int i = 0; i < 16; ++i) s += wred[i];
    s_blockoff = s;
  }
  const unsigned p = blockIdx.x * 1024u + (unsigned)tid;
  bool f = is_lyndon(p, 6);
  unsigned long long m = __ballot(f);
  if (lane == 0) wsum[wv] = __popcll(m);
  __syncthreads();
  if (tid == 0) {
    int s = 0;
    for (int i = 0; i < 16; ++i) { int t = wsum[i]; wsum[i] = s; s += t; }
  }
  __syncthreads();
  if (lane == 0) {
    mask64[blockIdx.x * 16 + wv]  = m;
    grp_off[blockIdx.x * 16 + wv] = s_blockoff + wsum[wv];
  }
}

// ---------- kernel 3: per-(batch, j1) algebra + L2..L5 + sparse L6 + A-store ----
//
// L = S + sum_n coef_n S^{(x)n}; A_i = sum_m coef_{m+1} P_i^{(m)} (levels 1..5).
// L6 = S6 + A5(x)S1 + A4(x)S2 + A3(x)S3 + A2(x)S4 + coef2*p1*S5.
// j1<4 (dense): A-arrays stored to ws for logsig_dense6. j1>=4: sparse point eval
// (counts 554/107/9/0). Gather ranges hardcoded (g_B*).
//
// LDS layout (16304 floats = 65.2 KiB; 2 blocks/CU):
//  PA@0[584] PB@584[584] | L5@1168[4096] | A2@5264[8] A3@5272[64] A4@5336[512]
//  A5@5848[4096] | S2C@9944[64] S3C@10008[528p] S4C@10536[4224p] S1C@14760[8]
//  MK@14768[512 ull] GO@15792[512 int]

#define SM_PA  0
#define SM_PB  584
#define SM_L5  1168
#define SM_A2  5264
#define SM_A3  5272
#define SM_A4  5336
#define SM_A5  5848
#define SM_S2  9944
#define SM_S3  10008
#define SM_S4  10536
#define SM_S1  14760
#define SM_MK  14768
#define SM_GO  15792
#define SM_TOT 16304

__device__ __forceinline__ int pad32(int i) { return i + (i >> 5); }

__global__ __launch_bounds__(1024)
void logsig_algebra(const float* __restrict__ sig,
                    const int* __restrict__ idx_table,
                    const ull* __restrict__ mask64,
                    const int* __restrict__ grp_off,
                    float* __restrict__ Aws,
                    float* __restrict__ out) {
  __shared__ __align__(16) float sm[SM_TOT];
  const int tid = threadIdx.x;
  const int bid = blockIdx.x;
  const int xcd = bid & 7;
  const int g   = bid >> 3;
  const int b   = xcd * 8 + (g >> 3);
  const int j1  = g & 7;

  const float* __restrict__ S  = sig + (size_t)b * NWIDTH;
  const float* __restrict__ S2 = S + 8;
  const float* __restrict__ S3 = S + 72;
  const float* __restrict__ S4 = S + 584;
  const float* __restrict__ S5 = S + 4680;
  const float* __restrict__ S6 = S + 37448;

  const float p1 = S[j1];
  ull* mkL = (ull*)(sm + SM_MK);
  int* goL = (int*)(sm + SM_GO);

  // ---- stage ----
  if (tid < 8)   sm[SM_S1 + tid] = S[tid];
  if (tid < 64)  sm[SM_S2 + tid] = S2[tid];
  if (tid < 512) sm[SM_S3 + pad32(tid)] = S3[tid];
  {
    float4 v = *(const float4*)(S4 + tid * 4);
    int i0 = tid * 4;
    sm[SM_S4 + pad32(i0)]     = v.x;
    sm[SM_S4 + pad32(i0 + 1)] = v.y;
    sm[SM_S4 + pad32(i0 + 2)] = v.z;
    sm[SM_S4 + pad32(i0 + 3)] = v.w;
  }
  float p5[4], l5i[4];
  {
    float4 v = *(const float4*)(S5 + j1 * 4096 + tid * 4);
    p5[0] = v.x; p5[1] = v.y; p5[2] = v.z; p5[3] = v.w;
    l5i[0] = v.x; l5i[1] = v.y; l5i[2] = v.z; l5i[3] = v.w;
  }
  if (tid < 512 && j1 >= 4) {
    mkL[tid] = mask64[j1 * 512 + tid];
    goL[tid] = grp_off[j1 * 512 + tid];
  }
  __syncthreads();

  float s1q[4];
#pragma unroll
  for (int e = 0; e < 4; ++e) s1q[e] = sm[SM_S1 + ((tid & 1) << 2) + e];
  const float s1t = sm[SM_S1 + (tid & 7)];
  if (tid < 8)   sm[SM_PA + tid]      = sm[SM_S2 + j1 * 8 + tid];
  if (tid < 64)  sm[SM_PA + 8 + tid]  = sm[SM_S3 + pad32(j1 * 64 + tid)];
  if (tid < 512) sm[SM_PA + 72 + tid] = sm[SM_S4 + pad32(j1 * 512 + tid)];
  __syncthreads();

  float a5[4] = {0.f, 0.f, 0.f, 0.f};
  float a4 = 0.f, a3 = 0.f, a2 = 0.f;

  // ---- Horner on P2..P5, ping-pong, 1 barrier/iter ----
  const float coefs[7] = {0.f, 0.f, -0.5f, 1.f / 3.f, -0.25f, 0.2f, -1.f / 6.f};
#pragma unroll
  for (int n = 2; n <= 5; ++n) {
    const float coef = coefs[n];
    const int RP = (n & 1) ? SM_PB : SM_PA;
    const int WP = (n & 1) ? SM_PA : SM_PB;
#pragma unroll
    for (int e = 0; e < 4; ++e) a5[e] += coef * p5[e];
    if (tid < 512) a4 += coef * sm[RP + 72 + tid];
    if (tid < 64)  a3 += coef * sm[RP + 8 + tid];
    if (tid < 8)   a2 += coef * sm[RP + tid];
    const float ph4 = sm[RP + 72 + (tid >> 1)];
    const float ph3 = sm[RP + 8 + (tid >> 4)];
    const float ph2 = sm[RP + (tid >> 7)];
    float np5[4];
#pragma unroll
    for (int e = 0; e < 4; ++e) {
      const int q = (tid << 2) + e;
      float acc = ph4 * s1q[e] + ph3 * sm[SM_S2 + (q & 63)]
                + ph2 * sm[SM_S3 + pad32(q & 511)];
      if (n == 2) acc += p1 * sm[SM_S4 + pad32(q)];
      np5[e] = acc;
    }
    float t4 = 0.f, t3 = 0.f, t2 = 0.f;
    if (tid < 512) {
      t4 = sm[RP + 8 + (tid >> 3)] * s1t
         + sm[RP + (tid >> 6)] * sm[SM_S2 + (tid & 63)];
      if (n == 2) t4 += p1 * sm[SM_S3 + pad32(tid)];
    }
    if (tid < 64) {
      t3 = sm[RP + (tid >> 3)] * s1t;
      if (n == 2) t3 += p1 * sm[SM_S2 + tid];
    }
    if (tid < 8) {
      if (n == 2) t2 = p1 * s1t;
    }
    if (tid < 512) sm[WP + 72 + tid] = t4;
    if (tid < 64)  sm[WP + 8 + tid]  = t3;
    if (tid < 8)   sm[WP + tid]      = t2;
#pragma unroll
    for (int e = 0; e < 4; ++e) p5[e] = np5[e];
    __syncthreads();
  }
#pragma unroll
  for (int e = 0; e < 4; ++e) a5[e] += coefs[6] * p5[e];   // n=6 (level 5 only)

  // ---- dump A to LDS; store to ws for dense j1 ----
  if (tid < 8)   sm[SM_A2 + tid] = a2;
  if (tid < 64)  sm[SM_A3 + tid] = a3;
  if (tid < 512) sm[SM_A4 + tid] = a4;
  *(float4*)(sm + SM_A5 + tid * 4) = make_float4(a5[0], a5[1], a5[2], a5[3]);
  if (j1 < 4) {
    float* Aw = Aws + (size_t)(b * 4 + j1) * 4680;
    if (tid < 8)   Aw[tid] = a2;
    if (tid < 64)  Aw[8 + tid] = a3;
    if (tid < 512) Aw[72 + tid] = a4;
    *(float4*)(Aw + 584 + tid * 4) = make_float4(a5[0], a5[1], a5[2], a5[3]);
  }
  __syncthreads();

  // ---- closed-form L2..L5 into LDS ----
  const float c2p1 = -0.5f * p1;
  if (tid < 8)
    sm[SM_PA + tid] = sm[SM_S2 + j1 * 8 + tid] + c2p1 * s1t;
  if (tid < 64)
    sm[SM_PA + 8 + tid] = sm[SM_S3 + pad32(j1 * 64 + tid)]
                        + sm[SM_A2 + (tid >> 3)] * s1t
                        + c2p1 * sm[SM_S2 + tid];
  if (tid < 512)
    sm[SM_PA + 72 + tid] = sm[SM_S4 + pad32(j1 * 512 + tid)]
                         + sm[SM_A3 + (tid >> 3)] * s1t
                         + sm[SM_A2 + (tid >> 6)] * sm[SM_S2 + (tid & 63)]
                         + c2p1 * sm[SM_S3 + pad32(tid)];
  {
    float l5v[4];
#pragma unroll
    for (int e = 0; e < 4; ++e) {
      const int q = (tid << 2) + e;
      l5v[e] = l5i[e]
             + sm[SM_A4 + (tid >> 1)] * s1q[e]
             + sm[SM_A3 + (tid >> 4)] * sm[SM_S2 + (q & 63)]
             + sm[SM_A2 + (tid >> 7)] * sm[SM_S3 + pad32(q & 511)]
             + c2p1 * sm[SM_S4 + pad32(q)];
    }
    *(float4*)(sm + SM_L5 + tid * 4) = make_float4(l5v[0], l5v[1], l5v[2], l5v[3]);
  }
  float* outb = out + (size_t)b * NOUT;
  if (tid == 0) outb[j1] = p1;
  __syncthreads();

  // ---- gather levels 2..5 (hardcoded ranges; j1 block-uniform) ----
  {
    int a0 = g_B2[j1], a1 = g_B2[j1 + 1], v0 = 8 + j1 * 8;
    for (int o = a0 + tid; o < a1; o += 1024)
      outb[o] = sm[SM_PA + (idx_table[o] - v0)];
  }
  {
    int a0 = g_B3[j1], a1 = g_B3[j1 + 1], v0 = 72 + j1 * 64;
    for (int o = a0 + tid; o < a1; o += 1024)
      outb[o] = sm[SM_PA + 8 + (idx_table[o] - v0)];
  }
  {
    int a0 = g_B4[j1], a1 = g_B4[j1 + 1], v0 = 584 + j1 * 512;
    for (int o = a0 + tid; o < a1; o += 1024)
      outb[o] = sm[SM_PA + 72 + (idx_table[o] - v0)];
  }
  {
    int a0 = g_B5[j1], a1 = g_B5[j1 + 1], v0 = 4680 + j1 * 4096;
    for (int o = a0 + tid; o < a1; o += 1024)
      outb[o] = sm[SM_L5 + (idx_table[o] - v0)];
  }

  // ---- level 6 sparse (j1 >= 4 only; dense handled by logsig_dense6) ----
  if (j1 >= 4 && tid < 512) {
    const float* __restrict__ S6j = S6 + (size_t)j1 * 32768;
    ull m = mkL[tid];
    int slot = 7764 + goL[tid];
    const int g6 = tid << 6;
    while (m) {
      const int bit = __builtin_ctzll(m);
      const int pl = g6 + bit;
      float v = S6j[pl]
              + sm[SM_A5 + (pl >> 3)] * sm[SM_S1 + (pl & 7)]
              + sm[SM_A4 + tid] * sm[SM_S2 + (pl & 63)]
              + sm[SM_A3 + (pl >> 9)] * sm[SM_S3 + pad32(pl & 511)]
              + sm[SM_A2 + (pl >> 12)] * sm[SM_S4 + pad32(pl & 4095)]
              + c2p1 * S5[pl];
      outb[slot++] = v;
      m &= m - 1;
    }
  }
}

// ---------- kernel 4: dense level-6 stream, uniform 512 blocks ----------
// block = (b, j1<4, half): streams 16384 positions of the (b,j1) slice.
// LDS 7968 floats (31.9 KiB):
//  S4C@0[4224p] S3C@4224[528p] A5C@4752[2048] A4C@6800[256] A3C@7056[64]
//  A2C@7120[8] S2C@7128[64] S1C@7192[8] MK@7200[512] GO@7712[256]

__global__ __launch_bounds__(1024)
void logsig_dense6(const float* __restrict__ sig,
                   const float* __restrict__ Aws,
                   const ull* __restrict__ mask64,
                   const int* __restrict__ grp_off,
                   float* __restrict__ out) {
  __shared__ __align__(16) float sm[7968];
  const int tid = threadIdx.x;
  const int bid = blockIdx.x;
  const int xcd = bid & 7, l = bid >> 3;
  const int b    = xcd * 8 + (l >> 3);
  const int j1   = (l >> 1) & 3;
  const int half = l & 1;

  const float* __restrict__ S   = sig + (size_t)b * NWIDTH;
  const float* __restrict__ S5  = S + 4680;
  const float* __restrict__ S6j = S + 37448 + (size_t)j1 * 32768;
  const float* __restrict__ Aw  = Aws + (size_t)(b * 4 + j1) * 4680;
  float* __restrict__ outb = out + (size_t)b * NOUT;

  float* S4C = sm;
  float* S3C = sm + 4224;
  float* A5C = sm + 4752;
  float* A4C = sm + 6800;
  float* A3C = sm + 7056;
  float* A2C = sm + 7120;
  float* S2C = sm + 7128;
  float* S1C = sm + 7192;
  ull*   MKL = (ull*)(sm + 7200);
  int*   GOL = (int*)(sm + 7712);

  {
    float4 v = *(const float4*)(S + 584 + tid * 4);
    int i0 = tid * 4;
    S4C[pad32(i0)]     = v.x;
    S4C[pad32(i0 + 1)] = v.y;
    S4C[pad32(i0 + 2)] = v.z;
    S4C[pad32(i0 + 3)] = v.w;
  }
  if (tid < 512) S3C[pad32(tid)] = S[72 + tid];
  if (tid < 64)  S2C[tid] = S[8 + tid];
  if (tid < 8)   S1C[tid] = S[tid];
  if (tid < 512) *(float4*)(A5C + tid * 4) =
      *(const float4*)(Aw + 584 + half * 2048 + tid * 4);
  if (tid < 256) A4C[tid] = Aw[72 + half * 256 + tid];
  if (tid < 64)  A3C[tid] = Aw[8 + tid];
  if (tid < 8)   A2C[tid] = Aw[tid];
  if (tid < 256) {
    MKL[tid] = mask64[j1 * 512 + half * 256 + tid];
    GOL[tid] = grp_off[j1 * 512 + half * 256 + tid];
  }
  __syncthreads();

  float s1q[4];
#pragma unroll
  for (int e = 0; e < 4; ++e) s1q[e] = S1C[((tid & 1) << 2) + e];
  const float c2p1 = -0.5f * S1C[j1];
  const int pbase = half * 16384;

#pragma unroll 4
  for (int it = 0; it < 4; ++it) {
    const int pl0 = it * 4096 + (tid << 2);
    const int pg  = pbase + pl0;
    const int gl  = pl0 >> 6;            // local group 0..255
    const ull m   = MKL[gl];
    const int gofs = GOL[gl];
    const float4 x6 = *(const float4*)(S6j + pg);
    const float4 x5 = *(const float4*)(S5 + pg);
    const float x6a[4] = {x6.x, x6.y, x6.z, x6.w};
    const float x5a[4] = {x5.x, x5.y, x5.z, x5.w};
    const float a5v = A5C[pl0 >> 3];
    const float a4v = A4C[gl];
    const float a3v = A3C[pg >> 9];
    const float a2v = A2C[pg >> 12];
    const int c63 = pl0 & 63, c511 = pl0 & 511, c4095 = pl0 & 4095;
#pragma unroll
    for (int e = 0; e < 4; ++e) {
      float v = x6a[e]
              + a5v * s1q[e]
              + a4v * S2C[c63 + e]
              + a3v * S3C[pad32(c511 + e)]
              + a2v * S4C[pad32(c4095 + e)]
              + c2p1 * x5a[e];
      if ((m >> (c63 + e)) & 1ull)
        outb[7764 + gofs + __popcll(m & ((1ull << (c63 + e)) - 1ull))] = v;
    }
  }
}

// ---------- launch ----------
// d_ws: mask64[4096] ull | idx_table[7764] int | blkcnt[256] | grp_off[4096] |
//       Aws[64*4*4680] float  (~4.9 MB total)

extern "C" void kernel_launch(void* const* d_in, const int* in_sizes, int n_in,
                              void* d_out, int out_size, void* d_ws, size_t ws_size,
                              hipStream_t stream) {
  const float* sig = (const float*)d_in[0];
  float* out = (float*)d_out;
  ull* mask64    = (ull*)d_ws;                       // 4096 ull
  int* idx_table = (int*)(mask64 + 4096);            // 7764 int
  int* blkcnt    = idx_table + 7764;                 // 256
  int* grp_off   = blkcnt + 256;                     // 4096
  float* Aws     = (float*)(grp_off + 4096);         // 64*4*4680 floats

  lyndon_stage1<<<257, 1024, 0, stream>>>(idx_table, blkcnt);
  lyndon6_finish<<<256, 1024, 0, stream>>>(blkcnt, mask64, grp_off);
  logsig_algebra<<<512, 1024, 0, stream>>>(sig, idx_table, mask64, grp_off, Aws, out);
  logsig_dense6<<<512, 1024, 0, stream>>>(sig, Aws, mask64, grp_off, out);
}

// Round 9
// 69.358 us; speedup vs baseline: 1.2228x; 1.0157x over previous
//
#include <hip/hip_runtime.h>

#define NWIDTH 299592
#define NOUT   51360

typedef unsigned long long ull;

// Hardcoded Lyndon gather ranges (fixed combinatorics, verified vs harness):
// level-k output-slot base per first letter j1 (9 entries: j1=0..7 + end).
__device__ const int g_B2[9] = {8, 15, 21, 26, 30, 33, 35, 36, 36};
__device__ const int g_B3[9] = {36, 92, 134, 164, 184, 196, 202, 204, 204};
__device__ const int g_B4[9] = {204, 624, 897, 1062, 1152, 1194, 1209, 1212, 1212};
__device__ const int g_B5[9] = {1212, 4404, 6210, 7140, 7560, 7716, 7758, 7764, 7764};

// ---------- Lyndon machinery (rebuilt every launch; deterministic) ----------

__device__ __forceinline__ bool is_lyndon(unsigned p, int n) {
  const unsigned nb = 3u * (unsigned)n;
  const unsigned mask = (1u << nb) - 1u;
  for (int k = 1; k < n; ++k) {
    unsigned rot = ((p << (3 * k)) & mask) | (p >> (nb - 3 * k));
    if (p >= rot) return false;   // strictly smaller than every proper rotation
  }
  return true;
}

// blocks 0..255: level-6 masks. block 256: levels 1..5 -> idx_table.
__global__ __launch_bounds__(1024) void lyndon_stage1(int* __restrict__ idx_table,
                                                      ull* __restrict__ mask64) {
  const int tid = threadIdx.x, lane = tid & 63, wv = tid >> 6;
  if (blockIdx.x < 256) {
    const unsigned p = blockIdx.x * 1024u + (unsigned)tid;
    bool f = is_lyndon(p, 6);
    ull m = __ballot(f);
    if (lane == 0) mask64[blockIdx.x * 16 + wv] = m;
    return;
  }
  __shared__ int ws[16];
  const int sizes[5] = {8, 64, 512, 4096, 32768};
  const int offs[5]  = {0, 8, 72, 584, 4680};     // sig flat offsets
  const int bases[5] = {0, 8, 36, 204, 1212};     // out slot bases
#pragma unroll
  for (int li = 0; li < 5; ++li) {
    const int n = li + 1, sz = sizes[li];
    const int per = (sz + 1023) >> 10;
    const int start = tid * per;
    int c = 0;
    for (int j = 0; j < per; ++j) {
      int p = start + j;
      if (p < sz && is_lyndon((unsigned)p, n)) ++c;
    }
    int pref = c;                                  // wave inclusive scan
    for (int d = 1; d < 64; d <<= 1) { int t = __shfl_up(pref, d); if (lane >= d) pref += t; }
    if (lane == 63) ws[wv] = pref;
    __syncthreads();
    int wbase = 0;
    for (int i = 0; i < wv; ++i) wbase += ws[i];
    int excl = wbase + pref - c;
    int w = 0;
    for (int j = 0; j < per; ++j) {
      int p = start + j;
      if (p < sz && is_lyndon((unsigned)p, n)) {
        idx_table[bases[li] + excl + w] = offs[li] + p;
        ++w;
      }
    }
    __syncthreads();
  }
}

// ONE block: popcount-scan the 4096 group masks -> global exclusive rank offsets.
__global__ __launch_bounds__(1024) void lyndon_finish(const ull* __restrict__ mask64,
                                                      int* __restrict__ grp_off) {
  __shared__ int ws[16];
  const int tid = threadIdx.x, lane = tid & 63, wv = tid >> 6;
  const int g0 = tid * 4;
  ull m0 = mask64[g0], m1 = mask64[g0 + 1], m2 = mask64[g0 + 2], m3 = mask64[g0 + 3];
  int p0 = __popcll(m0), p1 = __popcll(m1), p2 = __popcll(m2), p3 = __popcll(m3);
  int s = p0 + p1 + p2 + p3;
  int pref = s;
  for (int d = 1; d < 64; d <<= 1) { int t = __shfl_up(pref, d); if (lane >= d) pref += t; }
  if (lane == 63) ws[wv] = pref;
  __syncthreads();
  int base = 0;
  for (int i = 0; i < wv; ++i) base += ws[i];
  int run = base + pref - s;
  grp_off[g0] = run; run += p0;
  grp_off[g0 + 1] = run; run += p1;
  grp_off[g0 + 2] = run; run += p2;
  grp_off[g0 + 3] = run;
}

// ---------- kernel 3: per-(batch, j1<7) algebra + L2..L5 + sparse L6 + A-store --
//
// L = S + sum_n coef_n S^{(x)n}; A_i = sum_m coef_{m+1} P_i^{(m)} (levels 1..5).
// L6 = S6 + A5(x)S1 + A4(x)S2 + A3(x)S3 + A2(x)S4 + coef2*p1*S5.
// j1<4: A stored to ws for logsig_dense6. j1 in {4,5,6}: sparse point eval
// (554/107/9 words). j1=7 emits nothing beyond out[7] (done by j1=0 block).
// S3C/S4C unpadded: all hot reads are float4 (consecutive-16B/lane = conflict-free).
//
// LDS (16160 floats = 64.6 KiB; 2 blocks/CU):
//  PA@0[584] PB@584[584] L5@1168[4096] A2@5264[8] A3@5272[64] A4@5336[512]
//  A5@5848[4096] S2@9944[64] S3@10008[512] S4@10520[4096] S1@14616[8]
//  MK@14624[512 ull] GO@15648[512 int]

#define SM_PA  0
#define SM_PB  584
#define SM_L5  1168
#define SM_A2  5264
#define SM_A3  5272
#define SM_A4  5336
#define SM_A5  5848
#define SM_S2  9944
#define SM_S3  10008
#define SM_S4  10520
#define SM_S1  14616
#define SM_MK  14624
#define SM_GO  15648
#define SM_TOT 16160

__global__ __launch_bounds__(1024)
void logsig_algebra(const float* __restrict__ sig,
                    const int* __restrict__ idx_table,
                    const ull* __restrict__ mask64,
                    const int* __restrict__ grp_off,
                    float* __restrict__ Aws,
                    float* __restrict__ out) {
  __shared__ __align__(16) float sm[SM_TOT];
  const int tid = threadIdx.x;
  const int bid = blockIdx.x;
  const int xcd = bid & 7;
  const int g   = bid >> 3;          // 0..55
  const int b   = xcd * 8 + g / 7;
  const int j1  = g % 7;

  const float* __restrict__ S  = sig + (size_t)b * NWIDTH;
  const float* __restrict__ S2 = S + 8;
  const float* __restrict__ S3 = S + 72;
  const float* __restrict__ S4 = S + 584;
  const float* __restrict__ S5 = S + 4680;
  const float* __restrict__ S6 = S + 37448;

  const float p1 = S[j1];
  ull* mkL = (ull*)(sm + SM_MK);
  int* goL = (int*)(sm + SM_GO);

  // ---- stage (unpadded S3/S4) ----
  if (tid < 8)   sm[SM_S1 + tid] = S[tid];
  if (tid < 64)  sm[SM_S2 + tid] = S2[tid];
  if (tid < 512) sm[SM_S3 + tid] = S3[tid];
  *(float4*)(sm + SM_S4 + tid * 4) = *(const float4*)(S4 + tid * 4);
  float p5[4], l5i[4];
  {
    float4 v = *(const float4*)(S5 + j1 * 4096 + tid * 4);
    p5[0] = v.x; p5[1] = v.y; p5[2] = v.z; p5[3] = v.w;
    l5i[0] = v.x; l5i[1] = v.y; l5i[2] = v.z; l5i[3] = v.w;
  }
  if (tid < 512 && j1 >= 4) {
    mkL[tid] = mask64[j1 * 512 + tid];
    goL[tid] = grp_off[j1 * 512 + tid];
  }
  __syncthreads();

  float s1q[4];
#pragma unroll
  for (int e = 0; e < 4; ++e) s1q[e] = sm[SM_S1 + ((tid & 1) << 2) + e];
  const float s1t = sm[SM_S1 + (tid & 7)];
  if (tid < 8)   sm[SM_PA + tid]      = sm[SM_S2 + j1 * 8 + tid];
  if (tid < 64)  sm[SM_PA + 8 + tid]  = sm[SM_S3 + j1 * 64 + tid];
  if (tid < 512) sm[SM_PA + 72 + tid] = sm[SM_S4 + j1 * 512 + tid];
  __syncthreads();

  float a5[4] = {0.f, 0.f, 0.f, 0.f};
  float a4 = 0.f, a3 = 0.f, a2 = 0.f;
  const int q0 = tid << 2;

  // ---- Horner on P2..P5, ping-pong, 1 barrier/iter ----
  const float coefs[7] = {0.f, 0.f, -0.5f, 1.f / 3.f, -0.25f, 0.2f, -1.f / 6.f};
#pragma unroll
  for (int n = 2; n <= 5; ++n) {
    const float coef = coefs[n];
    const int RP = (n & 1) ? SM_PB : SM_PA;
    const int WP = (n & 1) ? SM_PA : SM_PB;
#pragma unroll
    for (int e = 0; e < 4; ++e) a5[e] += coef * p5[e];
    if (tid < 512) a4 += coef * sm[RP + 72 + tid];
    if (tid < 64)  a3 += coef * sm[RP + 8 + tid];
    if (tid < 8)   a2 += coef * sm[RP + tid];
    const float ph4 = sm[RP + 72 + (tid >> 1)];
    const float ph3 = sm[RP + 8 + (tid >> 4)];
    const float ph2 = sm[RP + (tid >> 7)];
    const float4 s2v = *(const float4*)(sm + SM_S2 + (q0 & 63));
    const float4 s3v = *(const float4*)(sm + SM_S3 + (q0 & 511));
    const float s2a[4] = {s2v.x, s2v.y, s2v.z, s2v.w};
    const float s3a[4] = {s3v.x, s3v.y, s3v.z, s3v.w};
    float np5[4];
    if (n == 2) {
      const float4 s4v = *(const float4*)(sm + SM_S4 + q0);
      const float s4a[4] = {s4v.x, s4v.y, s4v.z, s4v.w};
#pragma unroll
      for (int e = 0; e < 4; ++e)
        np5[e] = ph4 * s1q[e] + ph3 * s2a[e] + ph2 * s3a[e] + p1 * s4a[e];
    } else {
#pragma unroll
      for (int e = 0; e < 4; ++e)
        np5[e] = ph4 * s1q[e] + ph3 * s2a[e] + ph2 * s3a[e];
    }
    float t4 = 0.f, t3 = 0.f, t2 = 0.f;
    if (tid < 512) {
      t4 = sm[RP + 8 + (tid >> 3)] * s1t
         + sm[RP + (tid >> 6)] * sm[SM_S2 + (tid & 63)];
      if (n == 2) t4 += p1 * sm[SM_S3 + tid];
    }
    if (tid < 64) {
      t3 = sm[RP + (tid >> 3)] * s1t;
      if (n == 2) t3 += p1 * sm[SM_S2 + tid];
    }
    if (tid < 8) {
      if (n == 2) t2 = p1 * s1t;
    }
    if (tid < 512) sm[WP + 72 + tid] = t4;
    if (tid < 64)  sm[WP + 8 + tid]  = t3;
    if (tid < 8)   sm[WP + tid]      = t2;
#pragma unroll
    for (int e = 0; e < 4; ++e) p5[e] = np5[e];
    __syncthreads();
  }
#pragma unroll
  for (int e = 0; e < 4; ++e) a5[e] += coefs[6] * p5[e];   // n=6 (level 5 only)

  // ---- dump A to LDS; store to ws for dense j1 ----
  if (tid < 8)   sm[SM_A2 + tid] = a2;
  if (tid < 64)  sm[SM_A3 + tid] = a3;
  if (tid < 512) sm[SM_A4 + tid] = a4;
  *(float4*)(sm + SM_A5 + tid * 4) = make_float4(a5[0], a5[1], a5[2], a5[3]);
  if (j1 < 4) {
    float* Aw = Aws + (size_t)(b * 4 + j1) * 4680;
    if (tid < 8)   Aw[tid] = a2;
    if (tid < 64)  Aw[8 + tid] = a3;
    if (tid < 512) Aw[72 + tid] = a4;
    *(float4*)(Aw + 584 + tid * 4) = make_float4(a5[0], a5[1], a5[2], a5[3]);
  }
  __syncthreads();

  // ---- closed-form L2..L5 into LDS ----
  const float c2p1 = -0.5f * p1;
  if (tid < 8)
    sm[SM_PA + tid] = sm[SM_S2 + j1 * 8 + tid] + c2p1 * s1t;
  if (tid < 64)
    sm[SM_PA + 8 + tid] = sm[SM_S3 + j1 * 64 + tid]
                        + sm[SM_A2 + (tid >> 3)] * s1t
                        + c2p1 * sm[SM_S2 + tid];
  if (tid < 512)
    sm[SM_PA + 72 + tid] = sm[SM_S4 + j1 * 512 + tid]
                         + sm[SM_A3 + (tid >> 3)] * s1t
                         + sm[SM_A2 + (tid >> 6)] * sm[SM_S2 + (tid & 63)]
                         + c2p1 * sm[SM_S3 + tid];
  {
    const float4 s2v = *(const float4*)(sm + SM_S2 + (q0 & 63));
    const float4 s3v = *(const float4*)(sm + SM_S3 + (q0 & 511));
    const float4 s4v = *(const float4*)(sm + SM_S4 + q0);
    const float s2a[4] = {s2v.x, s2v.y, s2v.z, s2v.w};
    const float s3a[4] = {s3v.x, s3v.y, s3v.z, s3v.w};
    const float s4a[4] = {s4v.x, s4v.y, s4v.z, s4v.w};
    const float a4v = sm[SM_A4 + (tid >> 1)];
    const float a3v = sm[SM_A3 + (tid >> 4)];
    const float a2v = sm[SM_A2 + (tid >> 7)];
    float l5v[4];
#pragma unroll
    for (int e = 0; e < 4; ++e)
      l5v[e] = l5i[e] + a4v * s1q[e] + a3v * s2a[e] + a2v * s3a[e] + c2p1 * s4a[e];
    *(float4*)(sm + SM_L5 + tid * 4) = make_float4(l5v[0], l5v[1], l5v[2], l5v[3]);
  }
  float* outb = out + (size_t)b * NOUT;
  if (tid == 0) {
    outb[j1] = p1;
    if (j1 == 0) outb[7] = S[7];   // j1=7 block doesn't exist; its only output
  }
  __syncthreads();

  // ---- gather levels 2..5 (hardcoded ranges; j1 block-uniform) ----
  {
    int a0 = g_B2[j1], a1 = g_B2[j1 + 1], v0 = 8 + j1 * 8;
    for (int o = a0 + tid; o < a1; o += 1024)
      outb[o] = sm[SM_PA + (idx_table[o] - v0)];
  }
  {
    int a0 = g_B3[j1], a1 = g_B3[j1 + 1], v0 = 72 + j1 * 64;
    for (int o = a0 + tid; o < a1; o += 1024)
      outb[o] = sm[SM_PA + 8 + (idx_table[o] - v0)];
  }
  {
    int a0 = g_B4[j1], a1 = g_B4[j1 + 1], v0 = 584 + j1 * 512;
    for (int o = a0 + tid; o < a1; o += 1024)
      outb[o] = sm[SM_PA + 72 + (idx_table[o] - v0)];
  }
  {
    int a0 = g_B5[j1], a1 = g_B5[j1 + 1], v0 = 4680 + j1 * 4096;
    for (int o = a0 + tid; o < a1; o += 1024)
      outb[o] = sm[SM_L5 + (idx_table[o] - v0)];
  }

  // ---- level 6 sparse (j1 in {4,5,6}; dense handled by logsig_dense6) ----
  if (j1 >= 4 && tid < 512) {
    const float* __restrict__ S6j = S6 + (size_t)j1 * 32768;
    ull m = mkL[tid];
    int slot = 7764 + goL[tid];
    const int g6 = tid << 6;
    while (m) {
      const int bit = __builtin_ctzll(m);
      const int pl = g6 + bit;
      float v = S6j[pl]
              + sm[SM_A5 + (pl >> 3)] * sm[SM_S1 + (pl & 7)]
              + sm[SM_A4 + tid] * sm[SM_S2 + (pl & 63)]
              + sm[SM_A3 + (pl >> 9)] * sm[SM_S3 + (pl & 511)]
              + sm[SM_A2 + (pl >> 12)] * sm[SM_S4 + (pl & 4095)]
              + c2p1 * S5[pl];
      outb[slot++] = v;
      m &= m - 1;
    }
  }
}

// ---------- kernel 4: dense level-6 stream, uniform 512 blocks ----------
// block = (b, j1<4, half): streams 16384 positions of the (b,j1) slice.
// LDS 7824 floats (31.3 KiB), unpadded + float4 reads:
//  S4C@0[4096] S3C@4096[512] A5C@4608[2048] A4C@6656[256] A3C@6912[64]
//  A2C@6976[8] S2C@6984[64] S1C@7048[8] MK@7056[256 ull] GO@7568[256]

__global__ __launch_bounds__(1024)
void logsig_dense6(const float* __restrict__ sig,
                   const float* __restrict__ Aws,
                   const ull* __restrict__ mask64,
                   const int* __restrict__ grp_off,
                   float* __restrict__ out) {
  __shared__ __align__(16) float sm[7824];
  const int tid = threadIdx.x;
  const int bid = blockIdx.x;
  const int xcd = bid & 7, l = bid >> 3;
  const int b    = xcd * 8 + (l >> 3);
  const int j1   = (l >> 1) & 3;
  const int half = l & 1;

  const float* __restrict__ S   = sig + (size_t)b * NWIDTH;
  const float* __restrict__ S5  = S + 4680;
  const float* __restrict__ S6j = S + 37448 + (size_t)j1 * 32768;
  const float* __restrict__ Aw  = Aws + (size_t)(b * 4 + j1) * 4680;
  float* __restrict__ outb = out + (size_t)b * NOUT;

  float* S4C = sm;
  float* S3C = sm + 4096;
  float* A5C = sm + 4608;
  float* A4C = sm + 6656;
  float* A3C = sm + 6912;
  float* A2C = sm + 6976;
  float* S2C = sm + 6984;
  float* S1C = sm + 7048;
  ull*   MKL = (ull*)(sm + 7056);
  int*   GOL = (int*)(sm + 7568);

  *(float4*)(S4C + tid * 4) = *(const float4*)(S + 584 + tid * 4);
  if (tid < 512) S3C[tid] = S[72 + tid];
  if (tid < 64)  S2C[tid] = S[8 + tid];
  if (tid < 8)   S1C[tid] = S[tid];
  if (tid < 512) *(float4*)(A5C + tid * 4) =
      *(const float4*)(Aw + 584 + half * 2048 + tid * 4);
  if (tid < 256) A4C[tid] = Aw[72 + half * 256 + tid];
  if (tid < 64)  A3C[tid] = Aw[8 + tid];
  if (tid < 8)   A2C[tid] = Aw[tid];
  if (tid < 256) {
    MKL[tid] = mask64[j1 * 512 + half * 256 + tid];
    GOL[tid] = grp_off[j1 * 512 + half * 256 + tid];
  }
  __syncthreads();

  float s1q[4];
#pragma unroll
  for (int e = 0; e < 4; ++e) s1q[e] = S1C[((tid & 1) << 2) + e];
  const float c2p1 = -0.5f * S1C[j1];
  const int pbase = half * 16384;
  const int t4i = tid << 2;

#pragma unroll 4
  for (int it = 0; it < 4; ++it) {
    const int pl0 = it * 4096 + t4i;
    const int pg  = pbase + pl0;
    const int gl  = pl0 >> 6;            // local group 0..255
    const ull m   = MKL[gl];
    const int gofs = GOL[gl];
    const float4 x6 = *(const float4*)(S6j + pg);
    const float4 x5 = *(const float4*)(S5 + pg);
    const float x6a[4] = {x6.x, x6.y, x6.z, x6.w};
    const float x5a[4] = {x5.x, x5.y, x5.z, x5.w};
    const float a5v = A5C[pl0 >> 3];
    const float a4v = A4C[gl];
    const float a3v = A3C[pg >> 9];
    const float a2v = A2C[pg >> 12];
    const int c63 = pl0 & 63;
    const float4 s2v = *(const float4*)(S2C + c63);
    const float4 s3v = *(const float4*)(S3C + (pl0 & 511));
    const float4 s4v = *(const float4*)(S4C + (pl0 & 4095));
    const float s2a[4] = {s2v.x, s2v.y, s2v.z, s2v.w};
    const float s3a[4] = {s3v.x, s3v.y, s3v.z, s3v.w};
    const float s4a[4] = {s4v.x, s4v.y, s4v.z, s4v.w};
#pragma unroll
    for (int e = 0; e < 4; ++e) {
      float v = x6a[e]
              + a5v * s1q[e]
              + a4v * s2a[e]
              + a3v * s3a[e]
              + a2v * s4a[e]
              + c2p1 * x5a[e];
      if ((m >> (c63 + e)) & 1ull)
        outb[7764 + gofs + __popcll(m & ((1ull << (c63 + e)) - 1ull))] = v;
    }
  }
}

// ---------- launch ----------
// d_ws: mask64[4096] ull | idx_table[7764] int | grp_off[4096] int |
//       Aws[64*4*4680] float  (~4.9 MB total)

extern "C" void kernel_launch(void* const* d_in, const int* in_sizes, int n_in,
                              void* d_out, int out_size, void* d_ws, size_t ws_size,
                              hipStream_t stream) {
  const float* sig = (const float*)d_in[0];
  float* out = (float*)d_out;
  ull* mask64    = (ull*)d_ws;                       // 4096 ull
  int* idx_table = (int*)(mask64 + 4096);            // 7764 int
  int* grp_off   = idx_table + 7764;                 // 4096
  float* Aws     = (float*)(grp_off + 4096);         // 64*4*4680 floats

  lyndon_stage1<<<257, 1024, 0, stream>>>(idx_table, mask64);
  lyndon_finish<<<1, 1024, 0, stream>>>(mask64, grp_off);
  logsig_algebra<<<448, 1024, 0, stream>>>(sig, idx_table, mask64, grp_off, Aws, out);
  logsig_dense6<<<512, 1024, 0, stream>>>(sig, Aws, mask64, grp_off, out);
}

// Round 10
// 54.160 us; speedup vs baseline: 1.5660x; 1.2806x over previous
//
#include <hip/hip_runtime.h>

#define NWIDTH 299592
#define NOUT   51360

typedef unsigned long long ull;

// Closed-form Lyndon combinatorics (Witt formula; cross-checked against the
// test-validated tables of rounds 8-9):
// g_Bk[j1] = output-slot base of level-k words with first letter j1.
__device__ const int g_B2[8] = {8, 15, 21, 26, 30, 33, 35, 36};
__device__ const int g_B3[8] = {36, 92, 134, 164, 184, 196, 202, 204};
__device__ const int g_B4[8] = {204, 624, 897, 1062, 1152, 1194, 1209, 1212};
__device__ const int g_B5[8] = {1212, 4404, 6210, 7140, 7560, 7716, 7758, 7764};
// level-6: rank base within the level per first letter (counts 24052,11809,
// 5155,1910,554,107,9,0 -> cumulative):
__device__ const int g_C6[7] = {0, 24052, 35861, 41016, 42926, 43480, 43587};

__device__ __forceinline__ bool is_lyndon(unsigned p, int n) {
  const unsigned nb = 3u * (unsigned)n;
  const unsigned mask = (1u << nb) - 1u;
#pragma unroll
  for (int k = 1; k < 6; ++k) {
    if (k >= n) break;
    unsigned rot = ((p << (3 * k)) & mask) | (p >> (nb - 3 * k));
    if (p >= rot) return false;   // strictly smaller than every proper rotation
  }
  return true;
}

// ---------------- fused single-launch kernel ----------------
// grid 960 = 8 XCD x 8 batches x 15 units. unit u<7: algebra block (j1=u):
// Horner->A, closed-form L2..L5 in regs, local-Lyndon gathers, sparse L6
// (j1 in {4,5,6}). unit u>=7: dense L6 block (j1=(u-7)>>1 <4, half=(u-7)&1):
// local masks + mini-Horner (A2..A4 full, A5 own half) + coalesced stream +
// ballot-rank scatter. All Lyndon data computed in-block; no workspace.
//
// LDS (13120 floats = 52.5 KiB; 2 blocks/CU):
//  S4@0[4096] S3@4096[512] S2@4608[64] S1@4672[8] PA@4680[584] PB@5264[584]
//  A2@5848[8] A3@5856[64] A4@5920[512] A5@6432[4096]
//  MK@10528[512 ull] GO@11552[512 int] LB@12064[1024 int] WS@13088[16] W2@13104[16]

#define SM_S4  0
#define SM_S3  4096
#define SM_S2  4608
#define SM_S1  4672
#define SM_PA  4680
#define SM_PB  5264
#define SM_A2  5848
#define SM_A3  5856
#define SM_A4  5920
#define SM_A5  6432
#define SM_MK  10528
#define SM_GO  11552
#define SM_LB  12064
#define SM_WS  13088
#define SM_W2  13104
#define SM_TOT 13120

__global__ __launch_bounds__(1024)
void logsig_fused(const float* __restrict__ sig, float* __restrict__ out) {
  __shared__ __align__(16) float sm[SM_TOT];
  int* LB = (int*)(sm + SM_LB);
  ull* MK = (ull*)(sm + SM_MK);
  int* GO = (int*)(sm + SM_GO);
  int* WS = (int*)(sm + SM_WS);
  int* W2 = (int*)(sm + SM_W2);

  const int tid = threadIdx.x, lane = tid & 63, wv = tid >> 6;
  const int bid = blockIdx.x;
  const int xcd = bid & 7;
  const int rr  = bid >> 3;              // 0..119
  const int b   = xcd * 8 + rr / 15;
  const int u   = rr % 15;
  const bool isalg = (u < 7);
  const int j1   = isalg ? u : ((u - 7) >> 1);
  const int half = isalg ? 0 : ((u - 7) & 1);

  const float* __restrict__ S   = sig + (size_t)b * NWIDTH;
  const float* __restrict__ S5  = S + 4680;
  const float* __restrict__ S6j = S + 37448 + (size_t)j1 * 32768;
  float* __restrict__ outb = out + (size_t)b * NOUT;

  // ---- stage S1..S4 + own S5 slice ----
  *(float4*)(sm + SM_S4 + tid * 4) = *(const float4*)(S + 584 + tid * 4);
  if (tid < 512) sm[SM_S3 + tid] = S[72 + tid];
  if (tid < 64)  sm[SM_S2 + tid] = S[8 + tid];
  if (tid < 8)   sm[SM_S1 + tid] = S[tid];
  float p5[4], l5i[4], p5d[2];
  if (isalg) {
    float4 v = *(const float4*)(S5 + j1 * 4096 + tid * 4);
    p5[0] = v.x; p5[1] = v.y; p5[2] = v.z; p5[3] = v.w;
    l5i[0] = v.x; l5i[1] = v.y; l5i[2] = v.z; l5i[3] = v.w;
  } else {
    float2 v = *(const float2*)(S5 + j1 * 4096 + half * 2048 + tid * 2);
    p5d[0] = v.x; p5d[1] = v.y;
  }
  // ---- local level-6 mask eval (VALU; hides under the staging loads) ----
  if (!isalg) {
    const unsigned pb = ((unsigned)j1 << 15) | ((unsigned)half << 14);
    unsigned lm = 0;
#pragma unroll 4
    for (int i = 0; i < 16; ++i)
      if (is_lyndon(pb | (unsigned)(tid * 16 + i), 6)) lm |= 1u << i;
    LB[tid] = (int)lm;
    if (half) {                       // count first half of the slice
      const unsigned p0 = (unsigned)j1 << 15;
      int c1 = 0;
#pragma unroll 4
      for (int i = 0; i < 16; ++i)
        c1 += is_lyndon(p0 | (unsigned)(tid * 16 + i), 6) ? 1 : 0;
      for (int d = 32; d; d >>= 1) c1 += __shfl_down(c1, d);
      if (lane == 0) W2[wv] = c1;
    }
  } else if (j1 >= 4) {
    const unsigned pb = (unsigned)j1 << 15;
    unsigned lm = 0;
#pragma unroll 4
    for (int i = 0; i < 32; ++i)
      if (is_lyndon(pb | (unsigned)(tid * 32 + i), 6)) lm |= 1u << i;
    LB[tid] = (int)lm;
  }
  __syncthreads();

  // ---- common regs + PA init + mask combine ----
  float s1q[4];
#pragma unroll
  for (int e = 0; e < 4; ++e) s1q[e] = sm[SM_S1 + ((tid & 1) << 2) + e];
  const float s1t = sm[SM_S1 + (tid & 7)];
  const float p1 = sm[SM_S1 + j1];
  const float c2p1 = -0.5f * p1;
  if (tid < 8)   sm[SM_PA + tid]      = sm[SM_S2 + j1 * 8 + tid];
  if (tid < 64)  sm[SM_PA + 8 + tid]  = sm[SM_S3 + j1 * 64 + tid];
  if (tid < 512) sm[SM_PA + 72 + tid] = sm[SM_S4 + j1 * 512 + tid];

  int mpref = 0, mpc = 0;
  if (!isalg) {
    if (tid < 256) {
      ull m = (ull)(unsigned)LB[4 * tid]
            | ((ull)(unsigned)LB[4 * tid + 1] << 16)
            | ((ull)(unsigned)LB[4 * tid + 2] << 32)
            | ((ull)(unsigned)LB[4 * tid + 3] << 48);
      MK[tid] = m;
      mpc = __popcll(m);
      mpref = mpc;
      for (int d = 1; d < 64; d <<= 1) { int t = __shfl_up(mpref, d); if (lane >= d) mpref += t; }
      if (lane == 63) WS[wv] = mpref;
    }
  } else if (j1 >= 4) {
    if (tid < 512) {
      ull m = (ull)(unsigned)LB[2 * tid] | ((ull)(unsigned)LB[2 * tid + 1] << 32);
      MK[tid] = m;
      mpc = __popcll(m);
      mpref = mpc;
      for (int d = 1; d < 64; d <<= 1) { int t = __shfl_up(mpref, d); if (lane >= d) mpref += t; }
      if (lane == 63) WS[wv] = mpref;
    }
  }
  __syncthreads();

  // ---- rank offsets ----
  if (!isalg) {
    if (tid < 256) {
      int base = 0;
      for (int i = 0; i < wv; ++i) base += WS[i];
      int hb = 0;
      if (half) for (int i = 0; i < 16; ++i) hb += W2[i];
      GO[tid] = g_C6[j1] + hb + base + mpref - mpc;
    }
  } else if (j1 >= 4) {
    if (tid < 512) {
      int base = 0;
      for (int i = 0; i < wv; ++i) base += WS[i];
      GO[tid] = g_C6[j1] + base + mpref - mpc;
    }
  }

  const float coefs[7] = {0.f, 0.f, -0.5f, 1.f / 3.f, -0.25f, 0.2f, -1.f / 6.f};
  const int q0 = tid << 2;

  if (isalg) {
    // ================= algebra path =================
    float a5[4] = {0.f, 0.f, 0.f, 0.f};
    float a4 = 0.f, a3 = 0.f, a2 = 0.f;
#pragma unroll
    for (int n = 2; n <= 5; ++n) {
      const float coef = coefs[n];
      const int RP = (n & 1) ? SM_PB : SM_PA;
      const int WP = (n & 1) ? SM_PA : SM_PB;
#pragma unroll
      for (int e = 0; e < 4; ++e) a5[e] += coef * p5[e];
      if (tid < 512) a4 += coef * sm[RP + 72 + tid];
      if (tid < 64)  a3 += coef * sm[RP + 8 + tid];
      if (tid < 8)   a2 += coef * sm[RP + tid];
      const float ph4 = sm[RP + 72 + (tid >> 1)];
      const float ph3 = sm[RP + 8 + (tid >> 4)];
      const float ph2 = sm[RP + (tid >> 7)];
      const float4 s2v = *(const float4*)(sm + SM_S2 + (q0 & 63));
      const float4 s3v = *(const float4*)(sm + SM_S3 + (q0 & 511));
      const float s2a[4] = {s2v.x, s2v.y, s2v.z, s2v.w};
      const float s3a[4] = {s3v.x, s3v.y, s3v.z, s3v.w};
      float np5[4];
      if (n == 2) {
        const float4 s4v = *(const float4*)(sm + SM_S4 + q0);
        const float s4a[4] = {s4v.x, s4v.y, s4v.z, s4v.w};
#pragma unroll
        for (int e = 0; e < 4; ++e)
          np5[e] = ph4 * s1q[e] + ph3 * s2a[e] + ph2 * s3a[e] + p1 * s4a[e];
      } else {
#pragma unroll
        for (int e = 0; e < 4; ++e)
          np5[e] = ph4 * s1q[e] + ph3 * s2a[e] + ph2 * s3a[e];
      }
      float t4 = 0.f, t3 = 0.f, t2 = 0.f;
      if (tid < 512) {
        t4 = sm[RP + 8 + (tid >> 3)] * s1t
           + sm[RP + (tid >> 6)] * sm[SM_S2 + (tid & 63)];
        if (n == 2) t4 += p1 * sm[SM_S3 + tid];
      }
      if (tid < 64) {
        t3 = sm[RP + (tid >> 3)] * s1t;
        if (n == 2) t3 += p1 * sm[SM_S2 + tid];
      }
      if (tid < 8 && n == 2) t2 = p1 * s1t;
      if (tid < 512) sm[WP + 72 + tid] = t4;
      if (tid < 64)  sm[WP + 8 + tid]  = t3;
      if (tid < 8)   sm[WP + tid]      = t2;
#pragma unroll
      for (int e = 0; e < 4; ++e) p5[e] = np5[e];
      __syncthreads();
    }
#pragma unroll
    for (int e = 0; e < 4; ++e) a5[e] += coefs[6] * p5[e];   // n=6 (level 5 only)

    // dump A
    if (tid < 8)   sm[SM_A2 + tid] = a2;
    if (tid < 64)  sm[SM_A3 + tid] = a3;
    if (tid < 512) sm[SM_A4 + tid] = a4;
    *(float4*)(sm + SM_A5 + tid * 4) = make_float4(a5[0], a5[1], a5[2], a5[3]);
    __syncthreads();

    // closed-form L2..L5 in registers (owner threads)
    float l2v = 0.f, l3v = 0.f, l4v = 0.f, l5v[4];
    if (tid < 8)
      l2v = sm[SM_S2 + j1 * 8 + tid] + c2p1 * s1t;
    if (tid < 64)
      l3v = sm[SM_S3 + j1 * 64 + tid] + sm[SM_A2 + (tid >> 3)] * s1t
          + c2p1 * sm[SM_S2 + tid];
    if (tid < 512)
      l4v = sm[SM_S4 + j1 * 512 + tid] + sm[SM_A3 + (tid >> 3)] * s1t
          + sm[SM_A2 + (tid >> 6)] * sm[SM_S2 + (tid & 63)]
          + c2p1 * sm[SM_S3 + tid];
    {
      const float4 s2v = *(const float4*)(sm + SM_S2 + (q0 & 63));
      const float4 s3v = *(const float4*)(sm + SM_S3 + (q0 & 511));
      const float4 s4v = *(const float4*)(sm + SM_S4 + q0);
      const float s2a[4] = {s2v.x, s2v.y, s2v.z, s2v.w};
      const float s3a[4] = {s3v.x, s3v.y, s3v.z, s3v.w};
      const float s4a[4] = {s4v.x, s4v.y, s4v.z, s4v.w};
      const float a4v = sm[SM_A4 + (tid >> 1)];
      const float a3v = sm[SM_A3 + (tid >> 4)];
      const float a2v = sm[SM_A2 + (tid >> 7)];
#pragma unroll
      for (int e = 0; e < 4; ++e)
        l5v[e] = l5i[e] + a4v * s1q[e] + a3v * s2a[e] + a2v * s3a[e] + c2p1 * s4a[e];
    }
    if (tid == 0) {
      outb[j1] = p1;
      if (j1 == 0) outb[7] = sm[SM_S1 + 7];   // the absent j1=7 unit's only output
    }

    // ---- gathers (owner-thread local Lyndon + ballot ranks) ----
    // level 2: direct formula (lyndon <=> second letter > j1)
    if (tid < 8 && tid > j1) outb[g_B2[j1] + tid - j1 - 1] = l2v;
    // level 3: single wave
    if (tid < 64) {
      bool f = is_lyndon(((unsigned)j1 << 6) | (unsigned)tid, 3);
      ull m = __ballot(f);
      if (f) outb[g_B3[j1] + __popcll(m & ((1ull << lane) - 1ull))] = l3v;
    }
    // level 4 (waves 0..7) and level 5 (all) scans share one barrier
    bool f4 = (tid < 512) && is_lyndon(((unsigned)j1 << 9) | (unsigned)tid, 4);
    ull m4 = __ballot(f4);
    if (lane == 0) WS[wv] = __popcll(m4);
    bool f5[4];
    int c5 = 0;
#pragma unroll
    for (int e = 0; e < 4; ++e) {
      f5[e] = is_lyndon(((unsigned)j1 << 12) | (unsigned)(q0 + e), 5);
      c5 += f5[e] ? 1 : 0;
    }
    int pref5 = c5;
    for (int d = 1; d < 64; d <<= 1) { int t = __shfl_up(pref5, d); if (lane >= d) pref5 += t; }
    if (lane == 63) W2[wv] = pref5;
    __syncthreads();
    if (f4) {
      int base = 0;
      for (int i = 0; i < wv; ++i) base += WS[i];
      outb[g_B4[j1] + base + __popcll(m4 & ((1ull << lane) - 1ull))] = l4v;
    }
    {
      int base = 0;
      for (int i = 0; i < wv; ++i) base += W2[i];
      int slot = g_B5[j1] + base + pref5 - c5;
#pragma unroll
      for (int e = 0; e < 4; ++e)
        if (f5[e]) outb[slot++] = l5v[e];
    }

    // ---- sparse level 6 (j1 in {4,5,6}) ----
    if (j1 >= 4 && tid < 512) {
      ull m = MK[tid];
      int slot = 7764 + GO[tid];
      const int g6 = tid << 6;
      while (m) {
        const int bit = __builtin_ctzll(m);
        const int pl = g6 + bit;
        float v = S6j[pl]
                + sm[SM_A5 + (pl >> 3)] * sm[SM_S1 + (pl & 7)]
                + sm[SM_A4 + (pl >> 6)] * sm[SM_S2 + (pl & 63)]
                + sm[SM_A3 + (pl >> 9)] * sm[SM_S3 + (pl & 511)]
                + sm[SM_A2 + (pl >> 12)] * sm[SM_S4 + (pl & 4095)]
                + c2p1 * S5[pl];
        outb[slot++] = v;
        m &= m - 1;
      }
    }
  } else {
    // ================= dense level-6 path =================
    // mini-Horner: A2..A4 full, A5 own half (2 elems/thread)
    float a5d[2] = {0.f, 0.f};
    float a4 = 0.f, a3 = 0.f, a2 = 0.f;
    const int qd = half * 2048 + (tid << 1);       // own level-5 slice positions
    const float s1d0 = sm[SM_S1 + (qd & 7)];
    const float s1d1 = sm[SM_S1 + ((qd & 7) + 1)];
#pragma unroll
    for (int n = 2; n <= 5; ++n) {
      const float coef = coefs[n];
      const int RP = (n & 1) ? SM_PB : SM_PA;
      const int WP = (n & 1) ? SM_PA : SM_PB;
      a5d[0] += coef * p5d[0]; a5d[1] += coef * p5d[1];
      if (tid < 512) a4 += coef * sm[RP + 72 + tid];
      if (tid < 64)  a3 += coef * sm[RP + 8 + tid];
      if (tid < 8)   a2 += coef * sm[RP + tid];
      const float ph4 = sm[RP + 72 + (qd >> 3)];
      const float ph3 = sm[RP + 8 + (qd >> 6)];
      const float ph2 = sm[RP + (qd >> 9)];
      float np0 = ph4 * s1d0 + ph3 * sm[SM_S2 + (qd & 63)] + ph2 * sm[SM_S3 + (qd & 511)];
      float np1 = ph4 * s1d1 + ph3 * sm[SM_S2 + ((qd & 63) + 1)] + ph2 * sm[SM_S3 + ((qd & 511) + 1)];
      if (n == 2) {
        np0 += p1 * sm[SM_S4 + qd];
        np1 += p1 * sm[SM_S4 + qd + 1];
      }
      float t4 = 0.f, t3 = 0.f, t2 = 0.f;
      if (tid < 512) {
        t4 = sm[RP + 8 + (tid >> 3)] * s1t
           + sm[RP + (tid >> 6)] * sm[SM_S2 + (tid & 63)];
        if (n == 2) t4 += p1 * sm[SM_S3 + tid];
      }
      if (tid < 64) {
        t3 = sm[RP + (tid >> 3)] * s1t;
        if (n == 2) t3 += p1 * sm[SM_S2 + tid];
      }
      if (tid < 8 && n == 2) t2 = p1 * s1t;
      if (tid < 512) sm[WP + 72 + tid] = t4;
      if (tid < 64)  sm[WP + 8 + tid]  = t3;
      if (tid < 8)   sm[WP + tid]      = t2;
      p5d[0] = np0; p5d[1] = np1;
      __syncthreads();
    }
    a5d[0] += coefs[6] * p5d[0]; a5d[1] += coefs[6] * p5d[1];
    if (tid < 8)   sm[SM_A2 + tid] = a2;
    if (tid < 64)  sm[SM_A3 + tid] = a3;
    if (tid < 512) sm[SM_A4 + tid] = a4;
    sm[SM_A5 + (tid << 1)]     = a5d[0];           // local [0,2048)
    sm[SM_A5 + (tid << 1) + 1] = a5d[1];
    __syncthreads();

    // coalesced stream + ballot-rank scatter
    const int pbase = half * 16384;
    const int t4i = tid << 2;
#pragma unroll 4
    for (int it = 0; it < 4; ++it) {
      const int pl0 = it * 4096 + t4i;
      const int pg  = pbase + pl0;
      const int gl  = pl0 >> 6;
      const ull m   = MK[gl];
      const int gofs = GO[gl];
      const float4 x6 = *(const float4*)(S6j + pg);
      const float4 x5 = *(const float4*)(S5 + pg);
      const float x6a[4] = {x6.x, x6.y, x6.z, x6.w};
      const float x5a[4] = {x5.x, x5.y, x5.z, x5.w};
      const float a5v = sm[SM_A5 + (pl0 >> 3)];
      const float a4v = sm[SM_A4 + (pg >> 6)];
      const float a3v = sm[SM_A3 + (pg >> 9)];
      const float a2v = sm[SM_A2 + (pg >> 12)];
      const int c63 = pl0 & 63;
      const float4 s2v = *(const float4*)(sm + SM_S2 + c63);
      const float4 s3v = *(const float4*)(sm + SM_S3 + (pl0 & 511));
      const float4 s4v = *(const float4*)(sm + SM_S4 + (pl0 & 4095));
      const float s2a[4] = {s2v.x, s2v.y, s2v.z, s2v.w};
      const float s3a[4] = {s3v.x, s3v.y, s3v.z, s3v.w};
      const float s4a[4] = {s4v.x, s4v.y, s4v.z, s4v.w};
#pragma unroll
      for (int e = 0; e < 4; ++e) {
        float v = x6a[e]
                + a5v * s1q[e]
                + a4v * s2a[e]
                + a3v * s3a[e]
                + a2v * s4a[e]
                + c2p1 * x5a[e];
        if ((m >> (c63 + e)) & 1ull)
          outb[7764 + gofs + __popcll(m & ((1ull << (c63 + e)) - 1ull))] = v;
      }
    }
  }
}

// ---------- launch: ONE kernel, no workspace ----------

extern "C" void kernel_launch(void* const* d_in, const int* in_sizes, int n_in,
                              void* d_out, int out_size, void* d_ws, size_t ws_size,
                              hipStream_t stream) {
  const float* sig = (const float*)d_in[0];
  float* out = (float*)d_out;
  (void)d_ws; (void)ws_size; (void)in_sizes; (void)n_in; (void)out_size;
  logsig_fused<<<960, 1024, 0, stream>>>(sig, out);
}

// Round 11
// 50.539 us; speedup vs baseline: 1.6782x; 1.0717x over previous
//
#include <hip/hip_runtime.h>

#define NWIDTH 299592
#define NOUT   51360

typedef unsigned long long ull;

// Lyndon combinatorics (Witt formula; validated by rounds 8-10 passes):
__device__ const int g_B2[8] = {8, 15, 21, 26, 30, 33, 35, 36};
__device__ const int g_B3[8] = {36, 92, 134, 164, 184, 196, 202, 204};
__device__ const int g_B4[8] = {204, 624, 897, 1062, 1152, 1194, 1209, 1212};
__device__ const int g_B5[8] = {1212, 4404, 6210, 7140, 7560, 7716, 7758, 7764};
__device__ const int g_C6[7] = {0, 24052, 35861, 41016, 42926, 43480, 43587};

__device__ __forceinline__ bool is_lyndon6(unsigned p) {
  const unsigned mask = (1u << 18) - 1u;
#pragma unroll
  for (int k = 1; k < 6; ++k) {
    unsigned rot = ((p << (3 * k)) & mask) | (p >> (18 - 3 * k));
    if (p >= rot) return false;
  }
  return true;
}
__device__ __forceinline__ bool is_lyndon(unsigned p, int n) {
  const unsigned nb = 3u * (unsigned)n;
  const unsigned mask = (1u << nb) - 1u;
  for (int k = 1; k < n; ++k) {
    unsigned rot = ((p << (3 * k)) & mask) | (p >> (nb - 3 * k));
    if (p >= rot) return false;
  }
  return true;
}

// Unified LDS layout (floats). Algebra extent 7744; dense extent 9280.
#define L_S3  0       // 512
#define L_S2  512     // 64
#define L_S1  576     // 8
#define L_PA  584     // 584
#define L_PB  1168    // 584
#define L_A2  1752    // 8
#define L_A3  1760    // 64
#define L_A4  1824    // 512
#define L_WS  2336    // 8 int
#define L_W2  2344    // 8 int
#define L_W4  2352    // 8 int
#define L_W5  2360    // 8 int
#define L_GO  2368    // 256 int
#define L_A5  2624    // alg 4096 / dense 2048
#define L_S4D 4672    // dense only: 4096
#define L_MKA 6720    // alg only: 512 ull
#define L_MKD 8768    // dense only: 256 ull
#define L_TOT 9280    // 37.1 KiB -> 4 blocks/CU

__global__ __launch_bounds__(512)
void logsig_fused(const float* __restrict__ sig, float* __restrict__ out) {
  __shared__ __align__(16) float sm[L_TOT];
  int* WSi = (int*)(sm + L_WS);
  int* W2i = (int*)(sm + L_W2);
  int* W4i = (int*)(sm + L_W4);
  int* W5i = (int*)(sm + L_W5);
  int* GOi = (int*)(sm + L_GO);
  ull* MKa = (ull*)(sm + L_MKA);
  ull* MKd = (ull*)(sm + L_MKD);

  const int tid = threadIdx.x, lane = tid & 63, wv = tid >> 6;
  const int bid = blockIdx.x;
  const int xcd = bid & 7;
  const int rr  = bid >> 3;              // 0..119
  const int b   = xcd * 8 + rr / 15;
  const int u   = rr % 15;
  const bool isalg = (u < 7);
  const int j1   = isalg ? u : ((u - 7) >> 1);
  const int half = isalg ? 0 : ((u - 7) & 1);

  const float* __restrict__ S   = sig + (size_t)b * NWIDTH;
  const float* __restrict__ S4g = S + 584;
  const float* __restrict__ S5g = S + 4680;
  const float* __restrict__ S6j = S + 37448 + (size_t)j1 * 32768;
  float* __restrict__ outb = out + (size_t)b * NOUT;

  const float p1 = S[j1];                // uniform -> scalar
  const float c2p1 = -0.5f * p1;
  float s1v[8];
#pragma unroll
  for (int i = 0; i < 8; ++i) s1v[i] = S[i];   // uniform -> SGPRs

  // ---- stage ----
  sm[L_S3 + tid] = S[72 + tid];
  if (tid < 64) sm[L_S2 + tid] = S[8 + tid];
  if (tid < 8)  sm[L_S1 + tid] = S[tid];
  if (tid < 8)  sm[L_PA + tid]      = S[8 + j1 * 8 + tid];
  if (tid < 64) sm[L_PA + 8 + tid]  = S[72 + j1 * 64 + tid];
  sm[L_PA + 72 + tid] = S4g[j1 * 512 + tid];

  float p5[8];                 // alg: 8-wide level 5; dense: first 4 used
  float a5[8] = {0.f, 0.f, 0.f, 0.f, 0.f, 0.f, 0.f, 0.f};
  float a4 = 0.f, a3 = 0.f, a2 = 0.f;
  if (isalg) {
    float4 va = *(const float4*)(S5g + j1 * 4096 + tid * 8);
    float4 vb = *(const float4*)(S5g + j1 * 4096 + tid * 8 + 4);
    p5[0] = va.x; p5[1] = va.y; p5[2] = va.z; p5[3] = va.w;
    p5[4] = vb.x; p5[5] = vb.y; p5[6] = vb.z; p5[7] = vb.w;
  } else {
    float4 v = *(const float4*)(S5g + j1 * 4096 + half * 2048 + tid * 4);
    p5[0] = v.x; p5[1] = v.y; p5[2] = v.z; p5[3] = v.w;
    *(float4*)(sm + L_S4D + tid * 8)     = *(const float4*)(S4g + tid * 8);
    *(float4*)(sm + L_S4D + tid * 8 + 4) = *(const float4*)(S4g + tid * 8 + 4);
  }

  // ---- Lyndon masks / gather flags (VALU; overlaps staging latency) ----
  int mpref = 0, mpc = 0;
  ull mymask = 0, m4 = 0;
  unsigned fm5 = 0;
  int pref5 = 0, c5 = 0;
  if (isalg) {
    if (j1 >= 4) {
      const unsigned pb = ((unsigned)j1 << 15) | ((unsigned)tid << 6);
      ull m = 0;
      for (int i = 0; i < 64; ++i) {
        unsigned p = pb | (unsigned)i;
        if ((p & 0x24924u) == 0x24924u && is_lyndon6(p)) m |= (1ull << i);
      }
      mymask = m;
      MKa[tid] = m;
      mpc = __popcll(m); mpref = mpc;
      for (int d = 1; d < 64; d <<= 1) { int t = __shfl_up(mpref, d); if (lane >= d) mpref += t; }
      if (lane == 63) WSi[wv] = mpref;
    }
    bool f4 = is_lyndon(((unsigned)j1 << 9) | (unsigned)tid, 4);
    m4 = __ballot(f4);
    if (lane == 0) W4i[wv] = __popcll(m4);
#pragma unroll
    for (int e = 0; e < 8; ++e) {
      if (is_lyndon(((unsigned)j1 << 12) | (unsigned)(tid * 8 + e), 5)) { fm5 |= 1u << e; ++c5; }
    }
    pref5 = c5;
    for (int d = 1; d < 64; d <<= 1) { int t = __shfl_up(pref5, d); if (lane >= d) pref5 += t; }
    if (lane == 63) W5i[wv] = pref5;
  } else {
    if (tid < 256) {
      const unsigned pb = ((unsigned)j1 << 15) | ((unsigned)half << 14) | ((unsigned)tid << 6);
      ull m = 0;
      for (int i = 0; i < 64; ++i)
        if (is_lyndon6(pb | (unsigned)i)) m |= (1ull << i);
      MKd[tid] = m;
      mpc = __popcll(m); mpref = mpc;
      for (int d = 1; d < 64; d <<= 1) { int t = __shfl_up(mpref, d); if (lane >= d) mpref += t; }
      if (lane == 63) WSi[wv] = mpref;
    } else if (half) {
      const unsigned pb = ((unsigned)j1 << 15) | ((unsigned)(tid - 256) << 6);
      int c1 = 0;
      for (int i = 0; i < 64; ++i) c1 += is_lyndon6(pb | (unsigned)i) ? 1 : 0;
      for (int d = 32; d; d >>= 1) c1 += __shfl_down(c1, d);
      if (lane == 0) W2i[wv - 4] = c1;
    }
  }
  __syncthreads();

  const float s1t = sm[L_S1 + (tid & 7)];
  float s1q4[4];
#pragma unroll
  for (int e = 0; e < 4; ++e) s1q4[e] = sm[L_S1 + ((tid & 1) << 2) + e];

  // dense: per-group global rank offsets (consumed after the A-dump barrier)
  if (!isalg && tid < 256) {
    int hb = half ? (W2i[0] + W2i[1] + W2i[2] + W2i[3]) : 0;
    int base = 0;
    for (int i = 0; i < wv; ++i) base += WSi[i];
    GOi[tid] = g_C6[j1] + hb + base + mpref - mpc;
  }

  // ---- Horner n=2..5 (ping-pong; a-accumulate then overwrite p5 in place) ----
  const float coefs[7] = {0.f, 0.f, -0.5f, 1.f / 3.f, -0.25f, 0.2f, -1.f / 6.f};
#pragma unroll
  for (int n = 2; n <= 5; ++n) {
    const float coef = coefs[n];
    const int RP = (n & 1) ? L_PB : L_PA;
    const int WP = (n & 1) ? L_PA : L_PB;
    const float rp4o = sm[RP + 72 + tid];
    const float rp3  = sm[RP + 8 + (tid >> 3)];
    const float rp2  = sm[RP + (tid >> 6)];
    a4 += coef * rp4o;
    if (tid < 64) a3 += coef * sm[RP + 8 + tid];
    if (tid < 8)  a2 += coef * sm[RP + tid];
    float t4 = rp3 * s1t + rp2 * sm[L_S2 + (tid & 63)];
    if (n == 2) t4 += p1 * sm[L_S3 + tid];
    float t3 = 0.f, t2 = 0.f;
    if (tid < 64) {
      t3 = sm[RP + (tid >> 3)] * s1t;
      if (n == 2) t3 += p1 * sm[L_S2 + tid];
    }
    if (tid < 8 && n == 2) t2 = p1 * s1t;
    if (isalg) {
      // q = tid*8+e: q>>3 = tid (rp4o), q>>6 = tid>>3 (rp3), q>>9 = tid>>6 (rp2)
      const float4 s2a = *(const float4*)(sm + L_S2 + ((tid & 7) << 3));
      const float4 s2b = *(const float4*)(sm + L_S2 + ((tid & 7) << 3) + 4);
      const float4 s3a = *(const float4*)(sm + L_S3 + ((tid & 63) << 3));
      const float4 s3b = *(const float4*)(sm + L_S3 + ((tid & 63) << 3) + 4);
      const float s2q[8] = {s2a.x, s2a.y, s2a.z, s2a.w, s2b.x, s2b.y, s2b.z, s2b.w};
      const float s3q[8] = {s3a.x, s3a.y, s3a.z, s3a.w, s3b.x, s3b.y, s3b.z, s3b.w};
#pragma unroll
      for (int e = 0; e < 8; ++e) {
        a5[e] += coef * p5[e];
        p5[e] = rp4o * s1v[e] + rp3 * s2q[e] + rp2 * s3q[e];
      }
      if (n == 2) {
        const float4 s4a = *(const float4*)(S4g + tid * 8);
        const float4 s4b = *(const float4*)(S4g + tid * 8 + 4);
        const float s4q[8] = {s4a.x, s4a.y, s4a.z, s4a.w, s4b.x, s4b.y, s4b.z, s4b.w};
#pragma unroll
        for (int e = 0; e < 8; ++e) p5[e] += p1 * s4q[e];
      }
    } else {
      const int q = half * 2048 + tid * 4;
      const float rq4 = sm[RP + 72 + (q >> 3)];
      const float rq3 = sm[RP + 8 + (q >> 6)];
      const float rq2 = sm[RP + (q >> 9)];
      const float4 s2v = *(const float4*)(sm + L_S2 + (q & 63));
      const float4 s3v = *(const float4*)(sm + L_S3 + (q & 511));
      const float s2q[4] = {s2v.x, s2v.y, s2v.z, s2v.w};
      const float s3q[4] = {s3v.x, s3v.y, s3v.z, s3v.w};
#pragma unroll
      for (int e = 0; e < 4; ++e) {
        a5[e] += coef * p5[e];
        p5[e] = rq4 * s1q4[e] + rq3 * s2q[e] + rq2 * s3q[e];
      }
      if (n == 2) {
        const float4 s4v = *(const float4*)(sm + L_S4D + q);
        const float s4q[4] = {s4v.x, s4v.y, s4v.z, s4v.w};
#pragma unroll
        for (int e = 0; e < 4; ++e) p5[e] += p1 * s4q[e];
      }
    }
    sm[WP + 72 + tid] = t4;
    if (tid < 64) sm[WP + 8 + tid] = t3;
    if (tid < 8)  sm[WP + tid]     = t2;
    __syncthreads();
  }
  // n=6 contributes only via level 5
  if (isalg) {
#pragma unroll
    for (int e = 0; e < 8; ++e) a5[e] += coefs[6] * p5[e];
  } else {
#pragma unroll
    for (int e = 0; e < 4; ++e) a5[e] += coefs[6] * p5[e];
  }

  // ---- A dump ----
  sm[L_A4 + tid] = a4;
  if (tid < 64) sm[L_A3 + tid] = a3;
  if (tid < 8)  sm[L_A2 + tid] = a2;
  if (isalg) {
    *(float4*)(sm + L_A5 + tid * 8)     = make_float4(a5[0], a5[1], a5[2], a5[3]);
    *(float4*)(sm + L_A5 + tid * 8 + 4) = make_float4(a5[4], a5[5], a5[6], a5[7]);
  } else {
    *(float4*)(sm + L_A5 + tid * 4) = make_float4(a5[0], a5[1], a5[2], a5[3]);
  }
  __syncthreads();

  if (isalg) {
    // ---- closed-form L2..L5 + gathers ----
    float l2v = 0.f, l3v = 0.f;
    if (tid < 8)
      l2v = sm[L_S2 + j1 * 8 + tid] + c2p1 * s1t;
    if (tid < 64)
      l3v = sm[L_S3 + j1 * 64 + tid] + sm[L_A2 + (tid >> 3)] * s1t
          + c2p1 * sm[L_S2 + tid];
    const float l4v = S4g[j1 * 512 + tid] + sm[L_A3 + (tid >> 3)] * s1t
                    + sm[L_A2 + (tid >> 6)] * sm[L_S2 + (tid & 63)]
                    + c2p1 * sm[L_S3 + tid];
    float l5v[8];
    {
      const float4 va  = *(const float4*)(S5g + j1 * 4096 + tid * 8);
      const float4 vb  = *(const float4*)(S5g + j1 * 4096 + tid * 8 + 4);
      const float4 s4a = *(const float4*)(S4g + tid * 8);
      const float4 s4b = *(const float4*)(S4g + tid * 8 + 4);
      const float4 s2a = *(const float4*)(sm + L_S2 + ((tid & 7) << 3));
      const float4 s2b = *(const float4*)(sm + L_S2 + ((tid & 7) << 3) + 4);
      const float4 s3a = *(const float4*)(sm + L_S3 + ((tid & 63) << 3));
      const float4 s3b = *(const float4*)(sm + L_S3 + ((tid & 63) << 3) + 4);
      const float l5i[8] = {va.x, va.y, va.z, va.w, vb.x, vb.y, vb.z, vb.w};
      const float s4q[8] = {s4a.x, s4a.y, s4a.z, s4a.w, s4b.x, s4b.y, s4b.z, s4b.w};
      const float s2q[8] = {s2a.x, s2a.y, s2a.z, s2a.w, s2b.x, s2b.y, s2b.z, s2b.w};
      const float s3q[8] = {s3a.x, s3a.y, s3a.z, s3a.w, s3b.x, s3b.y, s3b.z, s3b.w};
      const float a4v = sm[L_A4 + tid];
      const float a3v = sm[L_A3 + (tid >> 3)];
      const float a2v = sm[L_A2 + (tid >> 6)];
#pragma unroll
      for (int e = 0; e < 8; ++e)
        l5v[e] = l5i[e] + a4v * s1v[e] + a3v * s2q[e] + a2v * s3q[e] + c2p1 * s4q[e];
    }
    if (tid == 0) {
      outb[j1] = p1;
      if (j1 == 0) outb[7] = s1v[7];
    }
    if (tid < 8 && tid > j1) outb[g_B2[j1] + tid - j1 - 1] = l2v;
    if (tid < 64) {
      bool f3 = is_lyndon(((unsigned)j1 << 6) | (unsigned)tid, 3);
      ull m3 = __ballot(f3);
      if (f3) outb[g_B3[j1] + __popcll(m3 & ((1ull << lane) - 1ull))] = l3v;
    }
    {
      int base = 0;
      for (int i = 0; i < wv; ++i) base += W4i[i];
      if ((m4 >> lane) & 1ull)
        outb[g_B4[j1] + base + __popcll(m4 & ((1ull << lane) - 1ull))] = l4v;
    }
    {
      int base = 0;
      for (int i = 0; i < wv; ++i) base += W5i[i];
      int slot = g_B5[j1] + base + pref5 - c5;
#pragma unroll
      for (int e = 0; e < 8; ++e)
        if ((fm5 >> e) & 1u) outb[slot++] = l5v[e];
    }
    // sparse level 6 (j1 in {4,5,6})
    if (j1 >= 4) {
      int base = 0;
      for (int i = 0; i < wv; ++i) base += WSi[i];
      int slot = 7764 + g_C6[j1] + base + mpref - mpc;
      ull m = mymask;
      const int g6 = tid << 6;
      while (m) {
        const int bit = __builtin_ctzll(m);
        const int pl = g6 + bit;
        float v = S6j[pl]
                + sm[L_A5 + (pl >> 3)] * sm[L_S1 + (pl & 7)]
                + sm[L_A4 + (pl >> 6)] * sm[L_S2 + (pl & 63)]
                + sm[L_A3 + (pl >> 9)] * sm[L_S3 + (pl & 511)]
                + sm[L_A2 + (pl >> 12)] * S4g[pl & 4095]
                + c2p1 * S5g[pl];
        outb[slot++] = v;
        m &= m - 1;
      }
    }
  } else {
    // ---- dense level-6 stream: 8 x float4 + ballot-rank scatter ----
    const int pbase = half * 16384;
    const int t4i = tid << 2;
#pragma unroll 4
    for (int it = 0; it < 8; ++it) {
      const int pl0 = it * 2048 + t4i;       // local [0,16384)
      const int pg  = pbase + pl0;
      const int gl  = pl0 >> 6;              // [0,256)
      const ull m   = MKd[gl];
      const int gofs = GOi[gl];
      const float4 x6 = *(const float4*)(S6j + pg);
      const float4 x5 = *(const float4*)(S5g + pg);
      const float x6a[4] = {x6.x, x6.y, x6.z, x6.w};
      const float x5a[4] = {x5.x, x5.y, x5.z, x5.w};
      const float a5v = sm[L_A5 + (pl0 >> 3)];
      const float a4v = sm[L_A4 + (pg >> 6)];
      const float a3v = sm[L_A3 + (pg >> 9)];
      const float a2v = sm[L_A2 + (pg >> 12)];
      const int c63 = pl0 & 63;
      const float4 s2v = *(const float4*)(sm + L_S2 + c63);
      const float4 s3v = *(const float4*)(sm + L_S3 + (pl0 & 511));
      const float4 s4v = *(const float4*)(sm + L_S4D + (pl0 & 4095));
      const float s2a[4] = {s2v.x, s2v.y, s2v.z, s2v.w};
      const float s3a[4] = {s3v.x, s3v.y, s3v.z, s3v.w};
      const float s4a[4] = {s4v.x, s4v.y, s4v.z, s4v.w};
#pragma unroll
      for (int e = 0; e < 4; ++e) {
        float v = x6a[e]
                + a5v * s1q4[e]
                + a4v * s2a[e]
                + a3v * s3a[e]
                + a2v * s4a[e]
                + c2p1 * x5a[e];
        if ((m >> (c63 + e)) & 1ull)
          outb[7764 + gofs + __popcll(m & ((1ull << (c63 + e)) - 1ull))] = v;
      }
    }
  }
}

// ---------- launch: ONE kernel, 960 x 512, no workspace ----------

extern "C" void kernel_launch(void* const* d_in, const int* in_sizes, int n_in,
                              void* d_out, int out_size, void* d_ws, size_t ws_size,
                              hipStream_t stream) {
  const float* sig = (const float*)d_in[0];
  float* out = (float*)d_out;
  (void)d_ws; (void)ws_size; (void)in_sizes; (void)n_in; (void)out_size;
  logsig_fused<<<960, 512, 0, stream>>>(sig, out);
}

// Round 12
// 41.278 us; speedup vs baseline: 2.0547x; 1.2244x over previous
//
#include <hip/hip_runtime.h>

#define NWIDTH 299592
#define NOUT   51360

typedef unsigned long long ull;

// Lyndon combinatorics (Witt formula; validated by rounds 8-11 passes):
__device__ const int g_B2[8] = {8, 15, 21, 26, 30, 33, 35, 36};
__device__ const int g_B3[8] = {36, 92, 134, 164, 184, 196, 202, 204};
__device__ const int g_B4[8] = {204, 624, 897, 1062, 1152, 1194, 1209, 1212};
__device__ const int g_B5[8] = {1212, 4404, 6210, 7140, 7560, 7716, 7758, 7764};
__device__ const int g_C6[7] = {0, 24052, 35861, 41016, 42926, 43480, 43587};

__device__ __forceinline__ bool is_lyndon6(unsigned p) {
  const unsigned mask = (1u << 18) - 1u;
#pragma unroll
  for (int k = 1; k < 6; ++k) {
    unsigned rot = ((p << (3 * k)) & mask) | (p >> (18 - 3 * k));
    if (p >= rot) return false;
  }
  return true;
}
__device__ __forceinline__ bool is_lyndon(unsigned p, int n) {
  const unsigned nb = 3u * (unsigned)n;
  const unsigned mask = (1u << nb) - 1u;
  for (int k = 1; k < n; ++k) {
    unsigned rot = ((p << (3 * k)) & mask) | (p >> (nb - 3 * k));
    if (p >= rot) return false;
  }
  return true;
}

// ---- prep: level-6 masks + global rank offsets, once (not per batch) ----
// block j = first letter (0..6). 32768 positions/block, 32/thread.
__global__ __launch_bounds__(1024) void lyndon_prep(ull* __restrict__ mask64g,
                                                    int* __restrict__ grp_offg) {
  __shared__ unsigned LB[1024];
  __shared__ int ex[1024];
  __shared__ int wsum[16];
  const int tid = threadIdx.x, lane = tid & 63, wv = tid >> 6;
  const int j = blockIdx.x;
  const unsigned pb = ((unsigned)j << 15) | ((unsigned)tid << 5);
  unsigned lm = 0;
  int c = 0;
  for (int i = 0; i < 32; ++i) {
    if (is_lyndon6(pb | (unsigned)i)) { lm |= 1u << i; ++c; }
  }
  LB[tid] = lm;
  int pref = c;
  for (int d = 1; d < 64; d <<= 1) { int t = __shfl_up(pref, d); if (lane >= d) pref += t; }
  if (lane == 63) wsum[wv] = pref;
  __syncthreads();
  int base = 0;
  for (int i = 0; i < wv; ++i) base += wsum[i];
  ex[tid] = base + pref - c;
  __syncthreads();
  if (tid < 512) {
    ull m = (ull)LB[2 * tid] | ((ull)LB[2 * tid + 1] << 32);
    mask64g[j * 512 + tid] = m;
    grp_offg[j * 512 + tid] = g_C6[j] + ex[2 * tid];
  }
}

// ---- main LDS layout (floats); algebra extent 6720, dense extent 9280 ----
#define L_S3  0       // 512
#define L_S2  512     // 64
#define L_S1  576     // 8
#define L_PA  584     // 584
#define L_PB  1168    // 584
#define L_A2  1752    // 8
#define L_A3  1760    // 64
#define L_A4  1824    // 512
#define L_W4  2336    // 8 int
#define L_W5  2344    // 8 int
#define L_GO  2352    // 256 int -> 2608
#define L_A5  2624    // alg 4096 / dense 2048
#define L_S4D 4672    // dense only: 4096 -> 8768
#define L_MKD 8768    // dense only: 256 ull -> 9280
#define L_TOT 9280    // 37.1 KiB -> 4 blocks/CU

__global__ __launch_bounds__(512)
void logsig_fused(const float* __restrict__ sig,
                  const ull* __restrict__ mask64g,
                  const int* __restrict__ grp_offg,
                  float* __restrict__ out) {
  __shared__ __align__(16) float sm[L_TOT];
  int* W4i = (int*)(sm + L_W4);
  int* W5i = (int*)(sm + L_W5);
  int* GOi = (int*)(sm + L_GO);
  ull* MKd = (ull*)(sm + L_MKD);

  const int tid = threadIdx.x, lane = tid & 63, wv = tid >> 6;
  const int bid = blockIdx.x;
  const int xcd = bid & 7;
  const int rr  = bid >> 3;              // 0..119
  const int b   = xcd * 8 + rr / 15;
  const int u   = rr % 15;
  const bool isalg = (u < 7);
  const int j1   = isalg ? u : ((u - 7) >> 1);
  const int half = isalg ? 0 : ((u - 7) & 1);

  const float* __restrict__ S   = sig + (size_t)b * NWIDTH;
  const float* __restrict__ S4g = S + 584;
  const float* __restrict__ S5g = S + 4680;
  const float* __restrict__ S6j = S + 37448 + (size_t)j1 * 32768;
  float* __restrict__ outb = out + (size_t)b * NOUT;

  const float p1 = S[j1];
  const float c2p1 = -0.5f * p1;
  const int q4 = tid << 2;

  // ---- stage (mask/rank loads first to overlap latency) ----
  ull sp_mk = 0; int sp_go = 0;
  if (isalg) {
    if (j1 >= 4) { sp_mk = mask64g[j1 * 512 + tid]; sp_go = grp_offg[j1 * 512 + tid]; }
  } else if (tid < 256) {
    MKd[tid] = mask64g[j1 * 512 + half * 256 + tid];
    GOi[tid] = grp_offg[j1 * 512 + half * 256 + tid];
  }
  sm[L_S3 + tid] = S[72 + tid];
  if (tid < 64) sm[L_S2 + tid] = S[8 + tid];
  if (tid < 8)  sm[L_S1 + tid] = S[tid];
  if (tid < 8)  sm[L_PA + tid]      = S[8 + j1 * 8 + tid];
  if (tid < 64) sm[L_PA + 8 + tid]  = S[72 + j1 * 64 + tid];
  sm[L_PA + 72 + tid] = S4g[j1 * 512 + tid];

  float p5[8];                 // alg: 2x4 (halves of level 5); dense: first 4
  float a5[8] = {0.f, 0.f, 0.f, 0.f, 0.f, 0.f, 0.f, 0.f};
  float a4 = 0.f, a3 = 0.f, a2 = 0.f;
  if (isalg) {
    float4 va = *(const float4*)(S5g + j1 * 4096 + q4);
    float4 vb = *(const float4*)(S5g + j1 * 4096 + 2048 + q4);
    p5[0] = va.x; p5[1] = va.y; p5[2] = va.z; p5[3] = va.w;
    p5[4] = vb.x; p5[5] = vb.y; p5[6] = vb.z; p5[7] = vb.w;
  } else {
    float4 v = *(const float4*)(S5g + j1 * 4096 + half * 2048 + q4);
    p5[0] = v.x; p5[1] = v.y; p5[2] = v.z; p5[3] = v.w;
    *(float4*)(sm + L_S4D + tid * 8)     = *(const float4*)(S4g + tid * 8);
    *(float4*)(sm + L_S4D + tid * 8 + 4) = *(const float4*)(S4g + tid * 8 + 4);
  }

  // ---- local gather flags for levels 4,5 (cheap; overlaps staging) ----
  ull m4 = 0;
  unsigned fm5a = 0, fm5b = 0;
  int exA = 0, exB = 0;
  if (isalg) {
    bool f4 = is_lyndon(((unsigned)j1 << 9) | (unsigned)tid, 4);
    m4 = __ballot(f4);
    if (lane == 0) W4i[wv] = __popcll(m4);
    int c5a = 0, c5b = 0;
#pragma unroll
    for (int e = 0; e < 4; ++e) {
      if (is_lyndon(((unsigned)j1 << 12) | (unsigned)(q4 + e), 5)) { fm5a |= 1u << e; ++c5a; }
      if (is_lyndon(((unsigned)j1 << 12) | (unsigned)(2048 + q4 + e), 5)) { fm5b |= 1u << e; ++c5b; }
    }
    int pk = c5a | (c5b << 16);
    int prefpk = pk;
    for (int d = 1; d < 64; d <<= 1) { int t = __shfl_up(prefpk, d); if (lane >= d) prefpk += t; }
    if (lane == 63) W5i[wv] = prefpk;
    exA = (prefpk & 0xffff) - c5a;
    exB = (prefpk >> 16) - c5b;
  }
  __syncthreads();

  const float s1t = sm[L_S1 + (tid & 7)];
  float s1q4[4];
#pragma unroll
  for (int e = 0; e < 4; ++e) s1q4[e] = sm[L_S1 + ((tid & 1) << 2) + e];

  // ---- Horner n=2..5 (ping-pong; a-accumulate then overwrite p5) ----
  const float coefs[7] = {0.f, 0.f, -0.5f, 1.f / 3.f, -0.25f, 0.2f, -1.f / 6.f};
#pragma unroll
  for (int n = 2; n <= 5; ++n) {
    const float coef = coefs[n];
    const int RP = (n & 1) ? L_PB : L_PA;
    const int WP = (n & 1) ? L_PA : L_PB;
    a4 += coef * sm[RP + 72 + tid];
    if (tid < 64) a3 += coef * sm[RP + 8 + tid];
    if (tid < 8)  a2 += coef * sm[RP + tid];
    float t4 = sm[RP + 8 + (tid >> 3)] * s1t
             + sm[RP + (tid >> 6)] * sm[L_S2 + (tid & 63)];
    if (n == 2) t4 += p1 * sm[L_S3 + tid];
    float t3 = 0.f, t2 = 0.f;
    if (tid < 64) {
      t3 = sm[RP + (tid >> 3)] * s1t;
      if (n == 2) t3 += p1 * sm[L_S2 + tid];
    }
    if (tid < 8 && n == 2) t2 = p1 * s1t;
    if (isalg) {
      const float rp4a = sm[RP + 72 + (tid >> 1)];
      const float rp4b = sm[RP + 72 + 256 + (tid >> 1)];
      const float rp3a = sm[RP + 8 + (tid >> 4)];
      const float rp3b = sm[RP + 8 + 32 + (tid >> 4)];
      const float rp2a = sm[RP + (tid >> 7)];
      const float rp2b = sm[RP + 4 + (tid >> 7)];
      const float4 s2v = *(const float4*)(sm + L_S2 + (q4 & 63));
      const float4 s3v = *(const float4*)(sm + L_S3 + (q4 & 511));
      const float s2q[4] = {s2v.x, s2v.y, s2v.z, s2v.w};
      const float s3q[4] = {s3v.x, s3v.y, s3v.z, s3v.w};
#pragma unroll
      for (int e = 0; e < 4; ++e) {
        a5[e]     += coef * p5[e];
        a5[4 + e] += coef * p5[4 + e];
        p5[e]     = rp4a * s1q4[e] + rp3a * s2q[e] + rp2a * s3q[e];
        p5[4 + e] = rp4b * s1q4[e] + rp3b * s2q[e] + rp2b * s3q[e];
      }
      if (n == 2) {
        const float4 s4va = *(const float4*)(S4g + q4);
        const float4 s4vb = *(const float4*)(S4g + 2048 + q4);
        const float s4qa[4] = {s4va.x, s4va.y, s4va.z, s4va.w};
        const float s4qb[4] = {s4vb.x, s4vb.y, s4vb.z, s4vb.w};
#pragma unroll
        for (int e = 0; e < 4; ++e) {
          p5[e] += p1 * s4qa[e];
          p5[4 + e] += p1 * s4qb[e];
        }
      }
    } else {
      const int q = half * 2048 + q4;
      const float rq4 = sm[RP + 72 + (q >> 3)];
      const float rq3 = sm[RP + 8 + (q >> 6)];
      const float rq2 = sm[RP + (q >> 9)];
      const float4 s2v = *(const float4*)(sm + L_S2 + (q & 63));
      const float4 s3v = *(const float4*)(sm + L_S3 + (q & 511));
      const float s2q[4] = {s2v.x, s2v.y, s2v.z, s2v.w};
      const float s3q[4] = {s3v.x, s3v.y, s3v.z, s3v.w};
#pragma unroll
      for (int e = 0; e < 4; ++e) {
        a5[e] += coef * p5[e];
        p5[e] = rq4 * s1q4[e] + rq3 * s2q[e] + rq2 * s3q[e];
      }
      if (n == 2) {
        const float4 s4v = *(const float4*)(sm + L_S4D + q);
        const float s4q[4] = {s4v.x, s4v.y, s4v.z, s4v.w};
#pragma unroll
        for (int e = 0; e < 4; ++e) p5[e] += p1 * s4q[e];
      }
    }
    sm[WP + 72 + tid] = t4;
    if (tid < 64) sm[WP + 8 + tid] = t3;
    if (tid < 8)  sm[WP + tid]     = t2;
    __syncthreads();
  }
#pragma unroll
  for (int e = 0; e < 8; ++e) a5[e] += coefs[6] * p5[e];   // n=6 (level 5 only)

  // ---- A dump ----
  sm[L_A4 + tid] = a4;
  if (tid < 64) sm[L_A3 + tid] = a3;
  if (tid < 8)  sm[L_A2 + tid] = a2;
  if (isalg) {
    *(float4*)(sm + L_A5 + q4)        = make_float4(a5[0], a5[1], a5[2], a5[3]);
    *(float4*)(sm + L_A5 + 2048 + q4) = make_float4(a5[4], a5[5], a5[6], a5[7]);
  } else {
    *(float4*)(sm + L_A5 + q4) = make_float4(a5[0], a5[1], a5[2], a5[3]);
  }
  __syncthreads();

  if (isalg) {
    // ---- closed-form L2..L5 ----
    float l2v = 0.f, l3v = 0.f;
    if (tid < 8)
      l2v = sm[L_S2 + j1 * 8 + tid] + c2p1 * s1t;
    if (tid < 64)
      l3v = sm[L_S3 + j1 * 64 + tid] + sm[L_A2 + (tid >> 3)] * s1t
          + c2p1 * sm[L_S2 + tid];
    const float l4v = S4g[j1 * 512 + tid] + sm[L_A3 + (tid >> 3)] * s1t
                    + sm[L_A2 + (tid >> 6)] * sm[L_S2 + (tid & 63)]
                    + c2p1 * sm[L_S3 + tid];
    float l5a[4], l5b[4];
    {
      const float4 via  = *(const float4*)(S5g + j1 * 4096 + q4);
      const float4 vib  = *(const float4*)(S5g + j1 * 4096 + 2048 + q4);
      const float4 s4va = *(const float4*)(S4g + q4);
      const float4 s4vb = *(const float4*)(S4g + 2048 + q4);
      const float4 s2v  = *(const float4*)(sm + L_S2 + (q4 & 63));
      const float4 s3v  = *(const float4*)(sm + L_S3 + (q4 & 511));
      const float l5ia[4] = {via.x, via.y, via.z, via.w};
      const float l5ib[4] = {vib.x, vib.y, vib.z, vib.w};
      const float s4qa[4] = {s4va.x, s4va.y, s4va.z, s4va.w};
      const float s4qb[4] = {s4vb.x, s4vb.y, s4vb.z, s4vb.w};
      const float s2q[4]  = {s2v.x, s2v.y, s2v.z, s2v.w};
      const float s3q[4]  = {s3v.x, s3v.y, s3v.z, s3v.w};
      const float a4a = sm[L_A4 + (tid >> 1)],  a4b = sm[L_A4 + 256 + (tid >> 1)];
      const float a3a = sm[L_A3 + (tid >> 4)],  a3b = sm[L_A3 + 32 + (tid >> 4)];
      const float a2a = sm[L_A2 + (tid >> 7)],  a2b = sm[L_A2 + 4 + (tid >> 7)];
#pragma unroll
      for (int e = 0; e < 4; ++e) {
        l5a[e] = l5ia[e] + a4a * s1q4[e] + a3a * s2q[e] + a2a * s3q[e] + c2p1 * s4qa[e];
        l5b[e] = l5ib[e] + a4b * s1q4[e] + a3b * s2q[e] + a2b * s3q[e] + c2p1 * s4qb[e];
      }
    }
    if (tid == 0) {
      outb[j1] = p1;
      if (j1 == 0) outb[7] = sm[L_S1 + 7];
    }
    if (tid < 8 && tid > j1) outb[g_B2[j1] + tid - j1 - 1] = l2v;
    if (tid < 64) {
      bool f3 = is_lyndon(((unsigned)j1 << 6) | (unsigned)tid, 3);
      ull m3 = __ballot(f3);
      if (f3) outb[g_B3[j1] + __popcll(m3 & ((1ull << lane) - 1ull))] = l3v;
    }
    {
      int base = 0;
      for (int i = 0; i < wv; ++i) base += W4i[i];
      if ((m4 >> lane) & 1ull)
        outb[g_B4[j1] + base + __popcll(m4 & ((1ull << lane) - 1ull))] = l4v;
    }
    {
      int baseA = 0, baseB = 0, totalA = 0;
#pragma unroll
      for (int i = 0; i < 8; ++i) {
        int w = W5i[i];
        totalA += w & 0xffff;
        if (i < wv) { baseA += w & 0xffff; baseB += w >> 16; }
      }
      int slotA = g_B5[j1] + baseA + exA;
      int slotB = g_B5[j1] + totalA + baseB + exB;
#pragma unroll
      for (int e = 0; e < 4; ++e)
        if ((fm5a >> e) & 1u) outb[slotA++] = l5a[e];
#pragma unroll
      for (int e = 0; e < 4; ++e)
        if ((fm5b >> e) & 1u) outb[slotB++] = l5b[e];
    }
    // ---- sparse level 6 (j1 in {4,5,6}) ----
    if (j1 >= 4) {
      ull m = sp_mk;
      int slot = 7764 + sp_go;
      const int g6 = tid << 6;
      while (m) {
        const int bit = __builtin_ctzll(m);
        const int pl = g6 + bit;
        float v = S6j[pl]
                + sm[L_A5 + (pl >> 3)] * sm[L_S1 + (pl & 7)]
                + sm[L_A4 + (pl >> 6)] * sm[L_S2 + (pl & 63)]
                + sm[L_A3 + (pl >> 9)] * sm[L_S3 + (pl & 511)]
                + sm[L_A2 + (pl >> 12)] * S4g[pl & 4095]
                + c2p1 * S5g[pl];
        outb[slot++] = v;
        m &= m - 1;
      }
    }
  } else {
    // ---- dense level-6 stream: 8 x float4 + ballot-rank scatter ----
    const int pbase = half * 16384;
#pragma unroll 4
    for (int it = 0; it < 8; ++it) {
      const int pl0 = it * 2048 + q4;        // local [0,16384)
      const int pg  = pbase + pl0;
      const int gl  = pl0 >> 6;              // [0,256)
      const ull m   = MKd[gl];
      const int gofs = GOi[gl];
      const float4 x6 = *(const float4*)(S6j + pg);
      const float4 x5 = *(const float4*)(S5g + pg);
      const float x6a[4] = {x6.x, x6.y, x6.z, x6.w};
      const float x5a[4] = {x5.x, x5.y, x5.z, x5.w};
      const float a5v = sm[L_A5 + (pl0 >> 3)];
      const float a4v = sm[L_A4 + (pg >> 6)];
      const float a3v = sm[L_A3 + (pg >> 9)];
      const float a2v = sm[L_A2 + (pg >> 12)];
      const int c63 = pl0 & 63;
      const float4 s2v = *(const float4*)(sm + L_S2 + c63);
      const float4 s3v = *(const float4*)(sm + L_S3 + (pl0 & 511));
      const float4 s4v = *(const float4*)(sm + L_S4D + (pl0 & 4095));
      const float s2a[4] = {s2v.x, s2v.y, s2v.z, s2v.w};
      const float s3a[4] = {s3v.x, s3v.y, s3v.z, s3v.w};
      const float s4a[4] = {s4v.x, s4v.y, s4v.z, s4v.w};
#pragma unroll
      for (int e = 0; e < 4; ++e) {
        float v = x6a[e]
                + a5v * s1q4[e]
                + a4v * s2a[e]
                + a3v * s3a[e]
                + a2v * s4a[e]
                + c2p1 * x5a[e];
        if ((m >> (c63 + e)) & 1ull)
          outb[7764 + gofs + __popcll(m & ((1ull << (c63 + e)) - 1ull))] = v;
      }
    }
  }
}

// ---------- launch ----------
// d_ws: mask64g[3584] ull | grp_offg[3584] int  (~42 KB)

extern "C" void kernel_launch(void* const* d_in, const int* in_sizes, int n_in,
                              void* d_out, int out_size, void* d_ws, size_t ws_size,
                              hipStream_t stream) {
  const float* sig = (const float*)d_in[0];
  float* out = (float*)d_out;
  ull* mask64g = (ull*)d_ws;                 // 7*512 ull
  int* grp_offg = (int*)(mask64g + 3584);    // 7*512 int

  lyndon_prep<<<7, 1024, 0, stream>>>(mask64g, grp_offg);
  logsig_fused<<<960, 512, 0, stream>>>(sig, mask64g, grp_offg, out);
}